// Round 1
// baseline (10521.313 us; speedup 1.0000x reference)
//
#include <hip/hip_runtime.h>

#define BN_EPS 1e-5f
#define KNN 20

static inline int ceildiv(int a, int b) { return (a + b - 1) / b; }

// ---------------- mm1: f1pre[b,n,c] = sum_d x[b,d,n] * w1[c,d] ----------------
__global__ void mm1_kernel(const float* __restrict__ x, const float* __restrict__ w1,
                           float* __restrict__ out, int N) {
    int c = threadIdx.x;               // 0..63
    int pl = threadIdx.y;              // 0..3
    int n = blockIdx.x * 4 + pl;
    int b = blockIdx.y;
    const float* xb = x + (size_t)b * 3 * N;
    float px = xb[n], py = xb[N + n], pz = xb[2 * N + n];
    float v = px * w1[c * 3 + 0] + py * w1[c * 3 + 1] + pz * w1[c * 3 + 2];
    out[((size_t)b * N + n) * 64 + c] = v;
}

// ---------------- BN stats (two-stage, deterministic) ----------------
__global__ void bn_stats1(const float* __restrict__ x, int R, int C, int chunks,
                          float* __restrict__ partial) {
    int c = blockIdx.x * 256 + threadIdx.x;
    int chunk = blockIdx.y;
    if (c >= C) return;
    int rows_per = (R + chunks - 1) / chunks;
    int r0 = chunk * rows_per;
    int r1 = min(R, r0 + rows_per);
    float s = 0.f, sq = 0.f;
    for (int r = r0; r < r1; ++r) {
        float v = x[(size_t)r * C + c];
        s += v; sq += v * v;
    }
    partial[(size_t)chunk * 2 * C + c] = s;
    partial[(size_t)chunk * 2 * C + C + c] = sq;
}

__global__ void bn_stats2(const float* __restrict__ partial, int C, int chunks, int R,
                          float* __restrict__ mv) {
    int c = blockIdx.x * 256 + threadIdx.x;
    if (c >= C) return;
    float s = 0.f, sq = 0.f;
    for (int k = 0; k < chunks; ++k) {
        s += partial[(size_t)k * 2 * C + c];
        sq += partial[(size_t)k * 2 * C + C + c];
    }
    float mean = s / (float)R;
    float var = sq / (float)R - mean * mean;
    mv[c] = mean;
    mv[C + c] = var;
}

__global__ void bn_apply(float* __restrict__ y, const float* __restrict__ mv,
                         const float* __restrict__ g, const float* __restrict__ bb,
                         int total, int C) {
    int i = blockIdx.x * 256 + threadIdx.x;
    if (i >= total) return;
    int c = i % C;
    float mean = mv[c], var = mv[C + c];
    float v = (y[i] - mean) * rsqrtf(var + BN_EPS) * g[c] + bb[c];
    y[i] = v >= 0.f ? v : 0.2f * v;
}

// ---------------- KNN top-20 (queries/candidates are prefixes of pts) ----------------
__global__ void knn_kernel(const float* __restrict__ x, int Nstride, int M, int N,
                           int* __restrict__ idx_out) {
    __shared__ float cx[256], cy[256], cz[256], cn[256];
    int b = blockIdx.y;
    int q = blockIdx.x * 256 + threadIdx.x;
    const float* xb = x + (size_t)b * 3 * Nstride;
    bool active = q < M;
    float qx = 0.f, qy = 0.f, qz = 0.f, qq = 0.f;
    if (active) {
        qx = xb[q]; qy = xb[Nstride + q]; qz = xb[2 * Nstride + q];
        qq = qx * qx + qy * qy + qz * qz;
    }
    float bd[KNN]; int bi[KNN];
#pragma unroll
    for (int k = 0; k < KNN; ++k) { bd[k] = 3.4e38f; bi[k] = 0; }
    float worst = 3.4e38f;

    for (int j0 = 0; j0 < N; j0 += 256) {
        int j = j0 + threadIdx.x;
        if (j < N) {
            float a = xb[j], bco = xb[Nstride + j], cco = xb[2 * Nstride + j];
            cx[threadIdx.x] = a; cy[threadIdx.x] = bco; cz[threadIdx.x] = cco;
            cn[threadIdx.x] = a * a + bco * bco + cco * cco;
        }
        __syncthreads();
        int jt = min(256, N - j0);
        if (active) {
            for (int t = 0; t < jt; ++t) {
                float dot = qx * cx[t] + qy * cy[t] + qz * cz[t];
                float d2 = qq + cn[t] - 2.f * dot;
                if (d2 < worst) {
                    int pos = KNN - 1;
                    while (pos > 0 && bd[pos - 1] > d2) {
                        bd[pos] = bd[pos - 1]; bi[pos] = bi[pos - 1]; --pos;
                    }
                    bd[pos] = d2; bi[pos] = j0 + t;
                    worst = bd[KNN - 1];
                }
            }
        }
        __syncthreads();
    }
    if (active) {
        int* o = idx_out + ((size_t)b * M + q) * KNN;
#pragma unroll
        for (int k = 0; k < KNN; ++k) o[k] = bi[k];
    }
}

// ---------------- gather + max over K neighbors ----------------
// out[b, m, out_off + c] (row stride out_stride) = max_k f[b, idx[b,m,k], c]
__global__ void pool_max_kernel(const float* __restrict__ f, const int* __restrict__ idx,
                                float* __restrict__ out, int M, int Nf, int C,
                                int out_stride, int out_off) {
    int c = threadIdx.x;   // blockDim.x == C (<=256)
    int m = blockIdx.x;
    int b = blockIdx.y;
    const int* ip = idx + ((size_t)b * M + m) * KNN;
    float v = -3.4e38f;
#pragma unroll
    for (int k = 0; k < KNN; ++k) {
        int j = ip[k];
        v = fmaxf(v, f[((size_t)b * Nf + j) * C + c]);
    }
    out[((size_t)b * M + m) * out_stride + out_off + c] = v;
}

// ---------------- GEMM: C[m,n] = sum_k A[m,k]*W[n,k] (+bias[n]) ----------------
__global__ void gemm_tn(const float* __restrict__ A, const float* __restrict__ W,
                        const float* __restrict__ bias, float* __restrict__ Cout,
                        int M, int N, int K) {
    __shared__ float As[16][17], Ws[16][17];
    int tx = threadIdx.x, ty = threadIdx.y;
    int row = blockIdx.x * 16 + ty;
    int col = blockIdx.y * 16 + tx;
    float acc = 0.f;
    for (int k0 = 0; k0 < K; k0 += 16) {
        int ar = blockIdx.x * 16 + ty;
        As[ty][tx] = (ar < M && (k0 + tx) < K) ? A[(size_t)ar * K + k0 + tx] : 0.f;
        int wr = blockIdx.y * 16 + ty;
        Ws[ty][tx] = (wr < N && (k0 + tx) < K) ? W[(size_t)wr * K + k0 + tx] : 0.f;
        __syncthreads();
#pragma unroll
        for (int kk = 0; kk < 16; ++kk) acc += As[ty][kk] * Ws[tx][kk];
        __syncthreads();
    }
    if (row < M && col < N) {
        if (bias) acc += bias[col];
        Cout[(size_t)row * N + col] = acc;
    }
}

// ---------------- global max+mean pool over rows ----------------
__global__ void global_pool_kernel(const float* __restrict__ h, float* __restrict__ out,
                                   int Rows, int C) {
    int c = blockIdx.x * 256 + threadIdx.x;
    int b = blockIdx.y;
    if (c >= C) return;
    const float* hb = h + (size_t)b * Rows * C;
    float m = -3.4e38f, s = 0.f;
    for (int r = 0; r < Rows; ++r) {
        float v = hb[(size_t)r * C + c];
        m = fmaxf(m, v); s += v;
    }
    out[(size_t)b * 2 * C + c] = m;
    out[(size_t)b * 2 * C + C + c] = s / (float)Rows;
}

extern "C" void kernel_launch(void* const* d_in, const int* in_sizes, int n_in,
                              void* d_out, int out_size, void* d_ws, size_t ws_size,
                              hipStream_t stream) {
    const int B = 16, N = 4096;
    const float* x   = (const float*)d_in[0];
    const float* w1  = (const float*)d_in[1];
    const float* g1  = (const float*)d_in[2];
    const float* b1  = (const float*)d_in[3];
    const float* w2  = (const float*)d_in[4];
    const float* g2  = (const float*)d_in[5];
    const float* b2  = (const float*)d_in[6];
    const float* w3  = (const float*)d_in[7];
    const float* g3  = (const float*)d_in[8];
    const float* b3  = (const float*)d_in[9];
    const float* w4  = (const float*)d_in[10];
    const float* g4  = (const float*)d_in[11];
    const float* b4  = (const float*)d_in[12];
    const float* w5  = (const float*)d_in[13];
    const float* g5  = (const float*)d_in[14];
    const float* b5  = (const float*)d_in[15];
    const float* l1w = (const float*)d_in[16];
    const float* g6  = (const float*)d_in[17];
    const float* b6  = (const float*)d_in[18];
    const float* l2w = (const float*)d_in[19];
    const float* l2b = (const float*)d_in[20];
    const float* g7  = (const float*)d_in[21];
    const float* b7  = (const float*)d_in[22];
    const float* l3w = (const float*)d_in[23];
    const float* l3b = (const float*)d_in[24];
    float* outp = (float*)d_out;

    // workspace carve-up
    char* ws = (char*)d_ws;
    size_t off = 0;
    auto alloc = [&](size_t bytes) -> void* {
        void* p = ws + off;
        off += (bytes + 255) & ~(size_t)255;
        return p;
    };
    float* f1    = (float*)alloc((size_t)B * 4096 * 64 * 4);
    float* f1p   = (float*)alloc((size_t)B * 1024 * 64 * 4);
    float* f2    = (float*)alloc((size_t)B * 1024 * 64 * 4);
    float* f2p   = (float*)alloc((size_t)B * 256 * 64 * 4);
    float* f3    = (float*)alloc((size_t)B * 256 * 128 * 4);
    float* f3p   = (float*)alloc((size_t)B * 128 * 128 * 4);
    float* f4    = (float*)alloc((size_t)B * 128 * 256 * 4);
    float* hcat  = (float*)alloc((size_t)B * 64 * 512 * 4);
    float* h5    = (float*)alloc((size_t)B * 64 * 1024 * 4);
    float* hg    = (float*)alloc((size_t)B * 2048 * 4);
    float* h6    = (float*)alloc((size_t)B * 512 * 4);
    float* h7    = (float*)alloc((size_t)B * 256 * 4);
    int* idxA = (int*)alloc((size_t)B * 1024 * KNN * 4);
    int* idxB = (int*)alloc((size_t)B * 64 * KNN * 4);
    int* idxC = (int*)alloc((size_t)B * 256 * KNN * 4);
    int* idxD = (int*)alloc((size_t)B * 64 * KNN * 4);
    int* idxE = (int*)alloc((size_t)B * 128 * KNN * 4);
    int* idxF = (int*)alloc((size_t)B * 64 * KNN * 4);
    float* partial = (float*)alloc((size_t)64 * 2 * 1024 * 4);
    float* mv      = (float*)alloc((size_t)2 * 1024 * 4);

    auto bn = [&](float* y, const float* g, const float* bb, int R, int C) {
        int chunks = (R >= 64) ? 64 : 1;
        bn_stats1<<<dim3(ceildiv(C, 256), chunks), 256, 0, stream>>>(y, R, C, chunks, partial);
        bn_stats2<<<dim3(ceildiv(C, 256)), 256, 0, stream>>>(partial, C, chunks, R, mv);
        int total = R * C;
        bn_apply<<<dim3(ceildiv(total, 256)), 256, 0, stream>>>(y, mv, g, bb, total, C);
    };
    auto gemm = [&](const float* A, const float* W, const float* bias, float* Cp,
                    int M, int Nn, int K) {
        gemm_tn<<<dim3(ceildiv(M, 16), ceildiv(Nn, 16)), dim3(16, 16), 0, stream>>>(
            A, W, bias, Cp, M, Nn, K);
    };

    // ---- stage 1: f1 = bn_lrelu(pts @ w1.T) : (B,4096,64)
    mm1_kernel<<<dim3(N / 4, B), dim3(64, 4), 0, stream>>>(x, w1, f1, N);
    bn(f1, g1, b1, B * N, 64);

    // ---- KNN index sets (all on prefix coordinate sets of x)
    knn_kernel<<<dim3(ceildiv(1024, 256), B), 256, 0, stream>>>(x, N, 1024, 4096, idxA);
    knn_kernel<<<dim3(1, B), 256, 0, stream>>>(x, N, 64, 1024, idxB);
    knn_kernel<<<dim3(1, B), 256, 0, stream>>>(x, N, 256, 1024, idxC);
    knn_kernel<<<dim3(1, B), 256, 0, stream>>>(x, N, 64, 256, idxD);
    knn_kernel<<<dim3(1, B), 256, 0, stream>>>(x, N, 128, 256, idxE);
    knn_kernel<<<dim3(1, B), 256, 0, stream>>>(x, N, 64, 128, idxF);

    // ---- pool1: f1p (B,1024,64); x1 -> hcat[:, :, 0:64]
    pool_max_kernel<<<dim3(1024, B), 64, 0, stream>>>(f1, idxA, f1p, 1024, 4096, 64, 64, 0);
    pool_max_kernel<<<dim3(64, B), 64, 0, stream>>>(f1p, idxB, hcat, 64, 1024, 64, 512, 0);

    // ---- stage 2: f2 = bn_lrelu(f1p @ w2.T) : (B,1024,64)
    gemm(f1p, w2, nullptr, f2, B * 1024, 64, 64);
    bn(f2, g2, b2, B * 1024, 64);
    pool_max_kernel<<<dim3(256, B), 64, 0, stream>>>(f2, idxC, f2p, 256, 1024, 64, 64, 0);
    pool_max_kernel<<<dim3(64, B), 64, 0, stream>>>(f2p, idxD, hcat, 64, 256, 64, 512, 64);

    // ---- stage 3: f3 = bn_lrelu(f2p @ w3.T) : (B,256,128)
    gemm(f2p, w3, nullptr, f3, B * 256, 128, 64);
    bn(f3, g3, b3, B * 256, 128);
    pool_max_kernel<<<dim3(128, B), 128, 0, stream>>>(f3, idxE, f3p, 128, 256, 128, 128, 0);
    pool_max_kernel<<<dim3(64, B), 128, 0, stream>>>(f3p, idxF, hcat, 64, 128, 128, 512, 128);

    // ---- stage 4: f4 = bn_lrelu(f3p @ w4.T) : (B,128,256)
    gemm(f3p, w4, nullptr, f4, B * 128, 256, 128);
    bn(f4, g4, b4, B * 128, 256);
    pool_max_kernel<<<dim3(64, B), 256, 0, stream>>>(f4, idxF, hcat, 64, 128, 256, 512, 256);

    // ---- stage 5: h5 = bn_lrelu(hcat @ w5.T) : (B,64,1024)
    gemm(hcat, w5, nullptr, h5, B * 64, 1024, 512);
    bn(h5, g5, b5, B * 64, 1024);

    // ---- global max+mean pool -> hg (B,2048)
    global_pool_kernel<<<dim3(ceildiv(1024, 256), B), 256, 0, stream>>>(h5, hg, 64, 1024);

    // ---- head
    gemm(hg, l1w, nullptr, h6, B, 512, 2048);
    bn(h6, g6, b6, B, 512);
    gemm(h6, l2w, l2b, h7, B, 256, 512);
    bn(h7, g7, b7, B, 256);
    gemm(h7, l3w, l3b, outp, B, 40, 256);
}

// Round 2
// 2285.625 us; speedup vs baseline: 4.6033x; 4.6033x over previous
//
#include <hip/hip_runtime.h>

#define BN_EPS 1e-5f
#define KNN 20

static inline int ceildiv(int a, int b) { return (a + b - 1) / b; }

// ---------------- mm1: f1pre[b,n,c] = sum_d x[b,d,n] * w1[c,d] ----------------
__global__ void mm1_kernel(const float* __restrict__ x, const float* __restrict__ w1,
                           float* __restrict__ out, int N) {
    int c = threadIdx.x;               // 0..63
    int pl = threadIdx.y;              // 0..3
    int n = blockIdx.x * 4 + pl;
    int b = blockIdx.y;
    const float* xb = x + (size_t)b * 3 * N;
    float px = xb[n], py = xb[N + n], pz = xb[2 * N + n];
    float v = px * w1[c * 3 + 0] + py * w1[c * 3 + 1] + pz * w1[c * 3 + 2];
    out[((size_t)b * N + n) * 64 + c] = v;
}

// ---------------- BN stats (two-stage, deterministic) ----------------
__global__ void bn_stats1(const float* __restrict__ x, int R, int C, int chunks,
                          float* __restrict__ partial) {
    int c = blockIdx.x * 256 + threadIdx.x;
    int chunk = blockIdx.y;
    if (c >= C) return;
    int rows_per = (R + chunks - 1) / chunks;
    int r0 = chunk * rows_per;
    int r1 = min(R, r0 + rows_per);
    float s = 0.f, sq = 0.f;
    for (int r = r0; r < r1; ++r) {
        float v = x[(size_t)r * C + c];
        s += v; sq += v * v;
    }
    partial[(size_t)chunk * 2 * C + c] = s;
    partial[(size_t)chunk * 2 * C + C + c] = sq;
}

__global__ void bn_stats2(const float* __restrict__ partial, int C, int chunks, int R,
                          float* __restrict__ mv) {
    int c = blockIdx.x * 256 + threadIdx.x;
    if (c >= C) return;
    float s = 0.f, sq = 0.f;
    for (int k = 0; k < chunks; ++k) {
        s += partial[(size_t)k * 2 * C + c];
        sq += partial[(size_t)k * 2 * C + C + c];
    }
    float mean = s / (float)R;
    float var = sq / (float)R - mean * mean;
    mv[c] = mean;
    mv[C + c] = var;
}

__global__ void bn_apply(float* __restrict__ y, const float* __restrict__ mv,
                         const float* __restrict__ g, const float* __restrict__ bb,
                         int total, int C) {
    int i = blockIdx.x * 256 + threadIdx.x;
    if (i >= total) return;
    int c = i % C;
    float mean = mv[c], var = mv[C + c];
    float v = (y[i] - mean) * rsqrtf(var + BN_EPS) * g[c] + bb[c];
    y[i] = v >= 0.f ? v : 0.2f * v;
}

// ---------------- KNN top-20: register compare-exchange chain ----------------
// Queries are prefix [0,M) of the candidate set; candidates are prefix [0,N).
// If nchunks==1: writes idx_out directly. Else: writes per-chunk candidate
// (d2, idx) lists to cand_d/cand_i at [b, q, chunk, k] for a later merge.
__global__ void knn_kernel(const float* __restrict__ x, int Nstride, int M, int N,
                           int chunk_size, int nchunks,
                           float* __restrict__ cand_d, int* __restrict__ cand_i,
                           int* __restrict__ idx_out) {
    __shared__ float cx[256], cy[256], cz[256], cn[256];
    int b = blockIdx.z;
    int chunk = blockIdx.y;
    int q = blockIdx.x * 256 + threadIdx.x;
    const float* xb = x + (size_t)b * 3 * Nstride;
    bool active = q < M;
    float qx = 0.f, qy = 0.f, qz = 0.f, qq = 0.f;
    if (active) {
        qx = xb[q]; qy = xb[Nstride + q]; qz = xb[2 * Nstride + q];
        qq = qx * qx + qy * qy + qz * qz;
    }
    float bd[KNN]; int bi[KNN];
#pragma unroll
    for (int k = 0; k < KNN; ++k) { bd[k] = 3.4e38f; bi[k] = 0; }

    int j0 = chunk * chunk_size;
    int j1 = min(N, j0 + chunk_size);
    for (int t0 = j0; t0 < j1; t0 += 256) {
        int j = t0 + threadIdx.x;
        if (j < j1) {
            float a = xb[j], bco = xb[Nstride + j], cco = xb[2 * Nstride + j];
            cx[threadIdx.x] = a; cy[threadIdx.x] = bco; cz[threadIdx.x] = cco;
            cn[threadIdx.x] = a * a + bco * bco + cco * cco;
        }
        __syncthreads();
        int jt = min(256, j1 - t0);
        if (active) {
            for (int t = 0; t < jt; ++t) {
                float d2 = qq + cn[t] - 2.f * (qx * cx[t] + qy * cy[t] + qz * cz[t]);
                if (d2 < bd[KNN - 1]) {
                    // stable register insertion: strict < keeps earlier (lower
                    // index) candidates ahead on ties, matching jax top_k.
                    float d = d2; int id = t0 + t;
#pragma unroll
                    for (int k = 0; k < KNN; ++k) {
                        bool sw = d < bd[k];
                        float td = bd[k]; int ti = bi[k];
                        bd[k] = sw ? d : td;  bi[k] = sw ? id : ti;
                        d = sw ? td : d;      id = sw ? ti : id;
                    }
                }
            }
        }
        __syncthreads();
    }
    if (active) {
        if (nchunks == 1) {
            int* o = idx_out + ((size_t)b * M + q) * KNN;
#pragma unroll
            for (int k = 0; k < KNN; ++k) o[k] = bi[k];
        } else {
            size_t base = (((size_t)b * M + q) * nchunks + chunk) * KNN;
#pragma unroll
            for (int k = 0; k < KNN; ++k) { cand_d[base + k] = bd[k]; cand_i[base + k] = bi[k]; }
        }
    }
}

// Merge nchunks sorted top-20 lists per query (chunk order = ascending index
// ranges, so sequential stable insertion preserves top_k tie semantics).
__global__ void knn_merge_kernel(const float* __restrict__ cand_d,
                                 const int* __restrict__ cand_i,
                                 int M, int nchunks, int* __restrict__ idx_out) {
    int b = blockIdx.y;
    int q = blockIdx.x * 256 + threadIdx.x;
    if (q >= M) return;
    const float* cd = cand_d + ((size_t)b * M + q) * nchunks * KNN;
    const int* ci = cand_i + ((size_t)b * M + q) * nchunks * KNN;
    float bd[KNN]; int bi[KNN];
#pragma unroll
    for (int k = 0; k < KNN; ++k) { bd[k] = 3.4e38f; bi[k] = 0; }
    int T = nchunks * KNN;
    for (int t = 0; t < T; ++t) {
        float d = cd[t]; int id = ci[t];
        if (d < bd[KNN - 1]) {
#pragma unroll
            for (int k = 0; k < KNN; ++k) {
                bool sw = d < bd[k];
                float td = bd[k]; int ti = bi[k];
                bd[k] = sw ? d : td;  bi[k] = sw ? id : ti;
                d = sw ? td : d;      id = sw ? ti : id;
            }
        }
    }
    int* o = idx_out + ((size_t)b * M + q) * KNN;
#pragma unroll
    for (int k = 0; k < KNN; ++k) o[k] = bi[k];
}

// ---------------- gather + max over K neighbors ----------------
__global__ void pool_max_kernel(const float* __restrict__ f, const int* __restrict__ idx,
                                float* __restrict__ out, int M, int Nf, int C,
                                int out_stride, int out_off) {
    int c = threadIdx.x;   // blockDim.x == C (<=256)
    int m = blockIdx.x;
    int b = blockIdx.y;
    const int* ip = idx + ((size_t)b * M + m) * KNN;
    float v = -3.4e38f;
#pragma unroll
    for (int k = 0; k < KNN; ++k) {
        int j = ip[k];
        v = fmaxf(v, f[((size_t)b * Nf + j) * C + c]);
    }
    out[((size_t)b * M + m) * out_stride + out_off + c] = v;
}

// ---------------- GEMM: C[m,n] = sum_k A[m,k]*W[n,k] (+bias[n]) ----------------
__global__ void gemm_tn(const float* __restrict__ A, const float* __restrict__ W,
                        const float* __restrict__ bias, float* __restrict__ Cout,
                        int M, int N, int K) {
    __shared__ float As[16][17], Ws[16][17];
    int tx = threadIdx.x, ty = threadIdx.y;
    int row = blockIdx.x * 16 + ty;
    int col = blockIdx.y * 16 + tx;
    float acc = 0.f;
    for (int k0 = 0; k0 < K; k0 += 16) {
        int ar = blockIdx.x * 16 + ty;
        As[ty][tx] = (ar < M && (k0 + tx) < K) ? A[(size_t)ar * K + k0 + tx] : 0.f;
        int wr = blockIdx.y * 16 + ty;
        Ws[ty][tx] = (wr < N && (k0 + tx) < K) ? W[(size_t)wr * K + k0 + tx] : 0.f;
        __syncthreads();
#pragma unroll
        for (int kk = 0; kk < 16; ++kk) acc += As[ty][kk] * Ws[tx][kk];
        __syncthreads();
    }
    if (row < M && col < N) {
        if (bias) acc += bias[col];
        Cout[(size_t)row * N + col] = acc;
    }
}

// ---------------- global max+mean pool over rows ----------------
__global__ void global_pool_kernel(const float* __restrict__ h, float* __restrict__ out,
                                   int Rows, int C) {
    int c = blockIdx.x * 256 + threadIdx.x;
    int b = blockIdx.y;
    if (c >= C) return;
    const float* hb = h + (size_t)b * Rows * C;
    float m = -3.4e38f, s = 0.f;
    for (int r = 0; r < Rows; ++r) {
        float v = hb[(size_t)r * C + c];
        m = fmaxf(m, v); s += v;
    }
    out[(size_t)b * 2 * C + c] = m;
    out[(size_t)b * 2 * C + C + c] = s / (float)Rows;
}

extern "C" void kernel_launch(void* const* d_in, const int* in_sizes, int n_in,
                              void* d_out, int out_size, void* d_ws, size_t ws_size,
                              hipStream_t stream) {
    const int B = 16, N = 4096;
    const float* x   = (const float*)d_in[0];
    const float* w1  = (const float*)d_in[1];
    const float* g1  = (const float*)d_in[2];
    const float* b1  = (const float*)d_in[3];
    const float* w2  = (const float*)d_in[4];
    const float* g2  = (const float*)d_in[5];
    const float* b2  = (const float*)d_in[6];
    const float* w3  = (const float*)d_in[7];
    const float* g3  = (const float*)d_in[8];
    const float* b3  = (const float*)d_in[9];
    const float* w4  = (const float*)d_in[10];
    const float* g4  = (const float*)d_in[11];
    const float* b4  = (const float*)d_in[12];
    const float* w5  = (const float*)d_in[13];
    const float* g5  = (const float*)d_in[14];
    const float* b5  = (const float*)d_in[15];
    const float* l1w = (const float*)d_in[16];
    const float* g6  = (const float*)d_in[17];
    const float* b6  = (const float*)d_in[18];
    const float* l2w = (const float*)d_in[19];
    const float* l2b = (const float*)d_in[20];
    const float* g7  = (const float*)d_in[21];
    const float* b7  = (const float*)d_in[22];
    const float* l3w = (const float*)d_in[23];
    const float* l3b = (const float*)d_in[24];
    float* outp = (float*)d_out;

    // workspace carve-up
    char* ws = (char*)d_ws;
    size_t off = 0;
    auto alloc = [&](size_t bytes) -> void* {
        void* p = ws + off;
        off += (bytes + 255) & ~(size_t)255;
        return p;
    };
    float* f1    = (float*)alloc((size_t)B * 4096 * 64 * 4);
    float* f1p   = (float*)alloc((size_t)B * 1024 * 64 * 4);
    float* f2    = (float*)alloc((size_t)B * 1024 * 64 * 4);
    float* f2p   = (float*)alloc((size_t)B * 256 * 64 * 4);
    float* f3    = (float*)alloc((size_t)B * 256 * 128 * 4);
    float* f3p   = (float*)alloc((size_t)B * 128 * 128 * 4);
    float* f4    = (float*)alloc((size_t)B * 128 * 256 * 4);
    float* hcat  = (float*)alloc((size_t)B * 64 * 512 * 4);
    float* h5    = (float*)alloc((size_t)B * 64 * 1024 * 4);
    float* hg    = (float*)alloc((size_t)B * 2048 * 4);
    float* h6    = (float*)alloc((size_t)B * 512 * 4);
    float* h7    = (float*)alloc((size_t)B * 256 * 4);
    int* idxA = (int*)alloc((size_t)B * 1024 * KNN * 4);
    int* idxB = (int*)alloc((size_t)B * 64 * KNN * 4);
    int* idxC = (int*)alloc((size_t)B * 256 * KNN * 4);
    int* idxD = (int*)alloc((size_t)B * 64 * KNN * 4);
    int* idxE = (int*)alloc((size_t)B * 128 * KNN * 4);
    int* idxF = (int*)alloc((size_t)B * 64 * KNN * 4);
    float* partial = (float*)alloc((size_t)64 * 2 * 1024 * 4);
    float* mv      = (float*)alloc((size_t)2 * 1024 * 4);

    // KNN-A chunked candidate scratch: overlaid on f2..h5 (written only AFTER
    // the merge has consumed it; all launches are stream-ordered).
    const int NCH = 4;                         // chunks for the 1024x4096 KNN
    float* candD = (float*)f2;                 // 16*1024*4*20*4 = 5.24 MB
    int*   candI = (int*)(candD + (size_t)B * 1024 * NCH * KNN);  // +5.24 MB
                                               // fits in f2..h5 span (~16.6 MB)

    auto bn = [&](float* y, const float* g, const float* bb, int R, int C) {
        int chunks = (R >= 64) ? 64 : 1;
        bn_stats1<<<dim3(ceildiv(C, 256), chunks), 256, 0, stream>>>(y, R, C, chunks, partial);
        bn_stats2<<<dim3(ceildiv(C, 256)), 256, 0, stream>>>(partial, C, chunks, R, mv);
        int total = R * C;
        bn_apply<<<dim3(ceildiv(total, 256)), 256, 0, stream>>>(y, mv, g, bb, total, C);
    };
    auto gemm = [&](const float* A, const float* W, const float* bias, float* Cp,
                    int M, int Nn, int K) {
        gemm_tn<<<dim3(ceildiv(M, 16), ceildiv(Nn, 16)), dim3(16, 16), 0, stream>>>(
            A, W, bias, Cp, M, Nn, K);
    };

    // ---- all KNN index sets first (read only x); A is chunked + merged
    knn_kernel<<<dim3(4, NCH, B), 256, 0, stream>>>(x, N, 1024, 4096, 4096 / NCH, NCH,
                                                    candD, candI, idxA);
    knn_merge_kernel<<<dim3(4, B), 256, 0, stream>>>(candD, candI, 1024, NCH, idxA);
    knn_kernel<<<dim3(1, 1, B), 256, 0, stream>>>(x, N, 64, 1024, 1024, 1, nullptr, nullptr, idxB);
    knn_kernel<<<dim3(1, 1, B), 256, 0, stream>>>(x, N, 256, 1024, 1024, 1, nullptr, nullptr, idxC);
    knn_kernel<<<dim3(1, 1, B), 256, 0, stream>>>(x, N, 64, 256, 256, 1, nullptr, nullptr, idxD);
    knn_kernel<<<dim3(1, 1, B), 256, 0, stream>>>(x, N, 128, 256, 256, 1, nullptr, nullptr, idxE);
    knn_kernel<<<dim3(1, 1, B), 256, 0, stream>>>(x, N, 64, 128, 128, 1, nullptr, nullptr, idxF);

    // ---- stage 1: f1 = bn_lrelu(pts @ w1.T) : (B,4096,64)
    mm1_kernel<<<dim3(N / 4, B), dim3(64, 4), 0, stream>>>(x, w1, f1, N);
    bn(f1, g1, b1, B * N, 64);

    // ---- pool1: f1p (B,1024,64); x1 -> hcat[:, :, 0:64]
    pool_max_kernel<<<dim3(1024, B), 64, 0, stream>>>(f1, idxA, f1p, 1024, 4096, 64, 64, 0);
    pool_max_kernel<<<dim3(64, B), 64, 0, stream>>>(f1p, idxB, hcat, 64, 1024, 64, 512, 0);

    // ---- stage 2: f2 = bn_lrelu(f1p @ w2.T) : (B,1024,64)
    gemm(f1p, w2, nullptr, f2, B * 1024, 64, 64);
    bn(f2, g2, b2, B * 1024, 64);
    pool_max_kernel<<<dim3(256, B), 64, 0, stream>>>(f2, idxC, f2p, 256, 1024, 64, 64, 0);
    pool_max_kernel<<<dim3(64, B), 64, 0, stream>>>(f2p, idxD, hcat, 64, 256, 64, 512, 64);

    // ---- stage 3: f3 = bn_lrelu(f2p @ w3.T) : (B,256,128)
    gemm(f2p, w3, nullptr, f3, B * 256, 128, 64);
    bn(f3, g3, b3, B * 256, 128);
    pool_max_kernel<<<dim3(128, B), 128, 0, stream>>>(f3, idxE, f3p, 128, 256, 128, 128, 0);
    pool_max_kernel<<<dim3(64, B), 128, 0, stream>>>(f3p, idxF, hcat, 64, 128, 128, 512, 128);

    // ---- stage 4: f4 = bn_lrelu(f3p @ w4.T) : (B,128,256)
    gemm(f3p, w4, nullptr, f4, B * 128, 256, 128);
    bn(f4, g4, b4, B * 128, 256);
    pool_max_kernel<<<dim3(64, B), 256, 0, stream>>>(f4, idxF, hcat, 64, 128, 256, 512, 256);

    // ---- stage 5: h5 = bn_lrelu(hcat @ w5.T) : (B,64,1024)
    gemm(hcat, w5, nullptr, h5, B * 64, 1024, 512);
    bn(h5, g5, b5, B * 64, 1024);

    // ---- global max+mean pool -> hg (B,2048)
    global_pool_kernel<<<dim3(ceildiv(1024, 256), B), 256, 0, stream>>>(h5, hg, 64, 1024);

    // ---- head
    gemm(hg, l1w, nullptr, h6, B, 512, 2048);
    bn(h6, g6, b6, B, 512);
    gemm(h6, l2w, l2b, h7, B, 256, 512);
    bn(h7, g7, b7, B, 256);
    gemm(h7, l3w, l3b, outp, B, 40, 256);
}

// Round 3
// 950.583 us; speedup vs baseline: 11.0683x; 2.4044x over previous
//
#include <hip/hip_runtime.h>

#define BN_EPS 1e-5f
#define KNN 20

static inline int ceildiv(int a, int b) { return (a + b - 1) / b; }

// ---------------- mm1: f1pre[b,n,c] = sum_d x[b,d,n] * w1[c,d] ----------------
__global__ void mm1_kernel(const float* __restrict__ x, const float* __restrict__ w1,
                           float* __restrict__ out, int N) {
    int c = threadIdx.x;               // 0..63
    int pl = threadIdx.y;              // 0..3
    int n = blockIdx.x * 4 + pl;
    int b = blockIdx.y;
    const float* xb = x + (size_t)b * 3 * N;
    float px = xb[n], py = xb[N + n], pz = xb[2 * N + n];
    float v = px * w1[c * 3 + 0] + py * w1[c * 3 + 1] + pz * w1[c * 3 + 2];
    out[((size_t)b * N + n) * 64 + c] = v;
}

// ---------------- BN stats (two-stage, deterministic) ----------------
__global__ void bn_stats1(const float* __restrict__ x, int R, int C, int chunks,
                          float* __restrict__ partial) {
    int c = blockIdx.x * 256 + threadIdx.x;
    int chunk = blockIdx.y;
    if (c >= C) return;
    int rows_per = (R + chunks - 1) / chunks;
    int r0 = chunk * rows_per;
    int r1 = min(R, r0 + rows_per);
    float s = 0.f, sq = 0.f;
    for (int r = r0; r < r1; ++r) {
        float v = x[(size_t)r * C + c];
        s += v; sq += v * v;
    }
    partial[(size_t)chunk * 2 * C + c] = s;
    partial[(size_t)chunk * 2 * C + C + c] = sq;
}

__global__ void bn_stats2(const float* __restrict__ partial, int C, int chunks, int R,
                          float* __restrict__ mv) {
    int c = blockIdx.x * 256 + threadIdx.x;
    if (c >= C) return;
    float s = 0.f, sq = 0.f;
    for (int k = 0; k < chunks; ++k) {
        s += partial[(size_t)k * 2 * C + c];
        sq += partial[(size_t)k * 2 * C + C + c];
    }
    float mean = s / (float)R;
    float var = sq / (float)R - mean * mean;
    mv[c] = mean;
    mv[C + c] = var;
}

__global__ void bn_apply(float* __restrict__ y, const float* __restrict__ mv,
                         const float* __restrict__ g, const float* __restrict__ bb,
                         int total, int C) {
    int i = blockIdx.x * 256 + threadIdx.x;
    if (i >= total) return;
    int c = i % C;
    float mean = mv[c], var = mv[C + c];
    float v = (y[i] - mean) * rsqrtf(var + BN_EPS) * g[c] + bb[c];
    y[i] = v >= 0.f ? v : 0.2f * v;
}

// ---------------- KNN top-20: one wave per query, lane-distributed list -------
// List element k lives in lane k (k<20), sorted ascending by (d2, idx).
// Per 64-candidate tile: each lane computes one distance; ballot gates
// survivors against the current 20th-best; survivors are broadcast and
// inserted via a cross-lane shift (shfl_up + cndmask). Arrival order is
// strictly increasing candidate index, so strict '<' reproduces jax top_k's
// lowest-index-first tie order.
__global__ void knn_wave_kernel(const float* __restrict__ x, int Nstride, int M, int N,
                                int* __restrict__ idx_out) {
    int b = blockIdx.y;
    int wave = threadIdx.x >> 6;           // 4 waves per block
    int lane = threadIdx.x & 63;
    int q = blockIdx.x * 4 + wave;
    if (q >= M) return;                    // wave-uniform
    const float* xb = x + (size_t)b * 3 * Nstride;
    float qx = xb[q], qy = xb[Nstride + q], qz = xb[2 * Nstride + q];
    float qq = qx * qx + qy * qy + qz * qz;

    float ld = 3.4e38f;                    // my list element (lane k = k-th best)
    int   li = 0;
    float w  = 3.4e38f;                    // current 20th-best (wave-uniform)

    for (int j0 = 0; j0 < N; j0 += 64) {
        int j = j0 + lane;
        float cxv = xb[j], cyv = xb[Nstride + j], czv = xb[2 * Nstride + j];
        float cn = cxv * cxv + cyv * cyv + czv * czv;
        float d2 = qq + cn - 2.f * (qx * cxv + qy * cyv + qz * czv);
        unsigned long long m = __ballot(d2 < w);
        while (m) {
            int src = (int)__ffsll(m) - 1;
            float d = __shfl(d2, src);
            int idx = j0 + src;
            if (d < w) {                   // wave-uniform re-check vs updated w
                float up_d = __shfl_up(ld, 1);
                int   up_i = __shfl_up(li, 1);
                bool c  = d < ld;
                bool cp = (lane != 0) && (d < up_d);
                ld = c ? (cp ? up_d : d) : ld;
                li = c ? (cp ? up_i : idx) : li;
                w = __shfl(ld, 19);
            }
            m &= m - 1;
        }
    }
    if (lane < KNN) idx_out[((size_t)b * M + q) * KNN + lane] = li;
}

// ---------------- gather + max over K neighbors ----------------
__global__ void pool_max_kernel(const float* __restrict__ f, const int* __restrict__ idx,
                                float* __restrict__ out, int M, int Nf, int C,
                                int out_stride, int out_off) {
    int c = threadIdx.x;   // blockDim.x == C (<=256)
    int m = blockIdx.x;
    int b = blockIdx.y;
    const int* ip = idx + ((size_t)b * M + m) * KNN;
    float v = -3.4e38f;
#pragma unroll
    for (int k = 0; k < KNN; ++k) {
        int j = ip[k];
        v = fmaxf(v, f[((size_t)b * Nf + j) * C + c]);
    }
    out[((size_t)b * M + m) * out_stride + out_off + c] = v;
}

// ---------------- GEMM: C[m,n] = sum_k A[m,k]*W[n,k] (+bias[n]) ----------------
__global__ void gemm_tn(const float* __restrict__ A, const float* __restrict__ W,
                        const float* __restrict__ bias, float* __restrict__ Cout,
                        int M, int N, int K) {
    __shared__ float As[16][17], Ws[16][17];
    int tx = threadIdx.x, ty = threadIdx.y;
    int row = blockIdx.x * 16 + ty;
    int col = blockIdx.y * 16 + tx;
    float acc = 0.f;
    for (int k0 = 0; k0 < K; k0 += 16) {
        int ar = blockIdx.x * 16 + ty;
        As[ty][tx] = (ar < M && (k0 + tx) < K) ? A[(size_t)ar * K + k0 + tx] : 0.f;
        int wr = blockIdx.y * 16 + ty;
        Ws[ty][tx] = (wr < N && (k0 + tx) < K) ? W[(size_t)wr * K + k0 + tx] : 0.f;
        __syncthreads();
#pragma unroll
        for (int kk = 0; kk < 16; ++kk) acc += As[ty][kk] * Ws[tx][kk];
        __syncthreads();
    }
    if (row < M && col < N) {
        if (bias) acc += bias[col];
        Cout[(size_t)row * N + col] = acc;
    }
}

// ---------------- global max+mean pool over rows ----------------
__global__ void global_pool_kernel(const float* __restrict__ h, float* __restrict__ out,
                                   int Rows, int C) {
    int c = blockIdx.x * 256 + threadIdx.x;
    int b = blockIdx.y;
    if (c >= C) return;
    const float* hb = h + (size_t)b * Rows * C;
    float m = -3.4e38f, s = 0.f;
    for (int r = 0; r < Rows; ++r) {
        float v = hb[(size_t)r * C + c];
        m = fmaxf(m, v); s += v;
    }
    out[(size_t)b * 2 * C + c] = m;
    out[(size_t)b * 2 * C + C + c] = s / (float)Rows;
}

extern "C" void kernel_launch(void* const* d_in, const int* in_sizes, int n_in,
                              void* d_out, int out_size, void* d_ws, size_t ws_size,
                              hipStream_t stream) {
    const int B = 16, N = 4096;
    const float* x   = (const float*)d_in[0];
    const float* w1  = (const float*)d_in[1];
    const float* g1  = (const float*)d_in[2];
    const float* b1  = (const float*)d_in[3];
    const float* w2  = (const float*)d_in[4];
    const float* g2  = (const float*)d_in[5];
    const float* b2  = (const float*)d_in[6];
    const float* w3  = (const float*)d_in[7];
    const float* g3  = (const float*)d_in[8];
    const float* b3  = (const float*)d_in[9];
    const float* w4  = (const float*)d_in[10];
    const float* g4  = (const float*)d_in[11];
    const float* b4  = (const float*)d_in[12];
    const float* w5  = (const float*)d_in[13];
    const float* g5  = (const float*)d_in[14];
    const float* b5  = (const float*)d_in[15];
    const float* l1w = (const float*)d_in[16];
    const float* g6  = (const float*)d_in[17];
    const float* b6  = (const float*)d_in[18];
    const float* l2w = (const float*)d_in[19];
    const float* l2b = (const float*)d_in[20];
    const float* g7  = (const float*)d_in[21];
    const float* b7  = (const float*)d_in[22];
    const float* l3w = (const float*)d_in[23];
    const float* l3b = (const float*)d_in[24];
    float* outp = (float*)d_out;

    // workspace carve-up
    char* ws = (char*)d_ws;
    size_t off = 0;
    auto alloc = [&](size_t bytes) -> void* {
        void* p = ws + off;
        off += (bytes + 255) & ~(size_t)255;
        return p;
    };
    float* f1    = (float*)alloc((size_t)B * 4096 * 64 * 4);
    float* f1p   = (float*)alloc((size_t)B * 1024 * 64 * 4);
    float* f2    = (float*)alloc((size_t)B * 1024 * 64 * 4);
    float* f2p   = (float*)alloc((size_t)B * 256 * 64 * 4);
    float* f3    = (float*)alloc((size_t)B * 256 * 128 * 4);
    float* f3p   = (float*)alloc((size_t)B * 128 * 128 * 4);
    float* f4    = (float*)alloc((size_t)B * 128 * 256 * 4);
    float* hcat  = (float*)alloc((size_t)B * 64 * 512 * 4);
    float* h5    = (float*)alloc((size_t)B * 64 * 1024 * 4);
    float* hg    = (float*)alloc((size_t)B * 2048 * 4);
    float* h6    = (float*)alloc((size_t)B * 512 * 4);
    float* h7    = (float*)alloc((size_t)B * 256 * 4);
    int* idxA = (int*)alloc((size_t)B * 1024 * KNN * 4);
    int* idxB = (int*)alloc((size_t)B * 64 * KNN * 4);
    int* idxC = (int*)alloc((size_t)B * 256 * KNN * 4);
    int* idxD = (int*)alloc((size_t)B * 64 * KNN * 4);
    int* idxE = (int*)alloc((size_t)B * 128 * KNN * 4);
    int* idxF = (int*)alloc((size_t)B * 64 * KNN * 4);
    float* partial = (float*)alloc((size_t)64 * 2 * 1024 * 4);
    float* mv      = (float*)alloc((size_t)2 * 1024 * 4);

    auto bn = [&](float* y, const float* g, const float* bb, int R, int C) {
        int chunks = (R >= 64) ? 64 : 1;
        bn_stats1<<<dim3(ceildiv(C, 256), chunks), 256, 0, stream>>>(y, R, C, chunks, partial);
        bn_stats2<<<dim3(ceildiv(C, 256)), 256, 0, stream>>>(partial, C, chunks, R, mv);
        int total = R * C;
        bn_apply<<<dim3(ceildiv(total, 256)), 256, 0, stream>>>(y, mv, g, bb, total, C);
    };
    auto gemm = [&](const float* A, const float* W, const float* bias, float* Cp,
                    int M, int Nn, int K) {
        gemm_tn<<<dim3(ceildiv(M, 16), ceildiv(Nn, 16)), dim3(16, 16), 0, stream>>>(
            A, W, bias, Cp, M, Nn, K);
    };
    auto knn = [&](int M, int Ncand, int* idx) {
        knn_wave_kernel<<<dim3(ceildiv(M, 4), B), 256, 0, stream>>>(x, N, M, Ncand, idx);
    };

    // ---- all KNN index sets (read only x; queries/candidates are prefixes)
    knn(1024, 4096, idxA);
    knn(64, 1024, idxB);
    knn(256, 1024, idxC);
    knn(64, 256, idxD);
    knn(128, 256, idxE);
    knn(64, 128, idxF);

    // ---- stage 1: f1 = bn_lrelu(pts @ w1.T) : (B,4096,64)
    mm1_kernel<<<dim3(N / 4, B), dim3(64, 4), 0, stream>>>(x, w1, f1, N);
    bn(f1, g1, b1, B * N, 64);

    // ---- pool1: f1p (B,1024,64); x1 -> hcat[:, :, 0:64]
    pool_max_kernel<<<dim3(1024, B), 64, 0, stream>>>(f1, idxA, f1p, 1024, 4096, 64, 64, 0);
    pool_max_kernel<<<dim3(64, B), 64, 0, stream>>>(f1p, idxB, hcat, 64, 1024, 64, 512, 0);

    // ---- stage 2: f2 = bn_lrelu(f1p @ w2.T) : (B,1024,64)
    gemm(f1p, w2, nullptr, f2, B * 1024, 64, 64);
    bn(f2, g2, b2, B * 1024, 64);
    pool_max_kernel<<<dim3(256, B), 64, 0, stream>>>(f2, idxC, f2p, 256, 1024, 64, 64, 0);
    pool_max_kernel<<<dim3(64, B), 64, 0, stream>>>(f2p, idxD, hcat, 64, 256, 64, 512, 64);

    // ---- stage 3: f3 = bn_lrelu(f2p @ w3.T) : (B,256,128)
    gemm(f2p, w3, nullptr, f3, B * 256, 128, 64);
    bn(f3, g3, b3, B * 256, 128);
    pool_max_kernel<<<dim3(128, B), 128, 0, stream>>>(f3, idxE, f3p, 128, 256, 128, 128, 0);
    pool_max_kernel<<<dim3(64, B), 128, 0, stream>>>(f3p, idxF, hcat, 64, 128, 128, 512, 128);

    // ---- stage 4: f4 = bn_lrelu(f3p @ w4.T) : (B,128,256)
    gemm(f3p, w4, nullptr, f4, B * 128, 256, 128);
    bn(f4, g4, b4, B * 128, 256);
    pool_max_kernel<<<dim3(64, B), 256, 0, stream>>>(f4, idxF, hcat, 64, 128, 256, 512, 256);

    // ---- stage 5: h5 = bn_lrelu(hcat @ w5.T) : (B,64,1024)
    gemm(hcat, w5, nullptr, h5, B * 64, 1024, 512);
    bn(h5, g5, b5, B * 64, 1024);

    // ---- global max+mean pool -> hg (B,2048)
    global_pool_kernel<<<dim3(ceildiv(1024, 256), B), 256, 0, stream>>>(h5, hg, 64, 1024);

    // ---- head
    gemm(hg, l1w, nullptr, h6, B, 512, 2048);
    bn(h6, g6, b6, B, 512);
    gemm(h6, l2w, l2b, h7, B, 256, 512);
    bn(h7, g7, b7, B, 256);
    gemm(h7, l3w, l3b, outp, B, 40, 256);
}

// Round 4
// 378.727 us; speedup vs baseline: 27.7808x; 2.5099x over previous
//
#include <hip/hip_runtime.h>

#define BN_EPS 1e-5f
#define KNN 20

static inline int ceildiv(int a, int b) { return (a + b - 1) / b; }

// ============ stage-1 moments: 9 sums over all points (Σp, Σppᵀ) ============
__global__ void moments3_kernel(const float* __restrict__ x, int N,
                                float* __restrict__ part /*[B][9]*/) {
    int b = blockIdx.x;
    int t = threadIdx.x;   // 256
    const float* xb = x + (size_t)b * 3 * N;
    float m[9] = {0, 0, 0, 0, 0, 0, 0, 0, 0};
    for (int n = t; n < N; n += 256) {
        float px = xb[n], py = xb[N + n], pz = xb[2 * N + n];
        m[0] += px; m[1] += py; m[2] += pz;
        m[3] += px * px; m[4] += py * py; m[5] += pz * pz;
        m[6] += px * py; m[7] += px * pz; m[8] += py * pz;
    }
#pragma unroll
    for (int o = 32; o; o >>= 1)
#pragma unroll
        for (int i = 0; i < 9; ++i) m[i] += __shfl_down(m[i], o);
    __shared__ float red[4][9];
    if ((t & 63) == 0)
#pragma unroll
        for (int i = 0; i < 9; ++i) red[t >> 6][i] = m[i];
    __syncthreads();
    if (t == 0) {
#pragma unroll
        for (int i = 0; i < 9; ++i)
            part[b * 9 + i] = red[0][i] + red[1][i] + red[2][i] + red[3][i];
    }
}

// scale/shift for stage 1 from the 9 moments + w1 rows
__global__ void finalize1_kernel(const float* __restrict__ part, const float* __restrict__ w1,
                                 const float* __restrict__ g, const float* __restrict__ bb,
                                 float* __restrict__ scsh, float Rinv, int Bn) {
    __shared__ float S[9];
    int t = threadIdx.x;   // 64
    if (t < 9) {
        float s = 0.f;
        for (int b = 0; b < Bn; ++b) s += part[b * 9 + t];
        S[t] = s;
    }
    __syncthreads();
    float wx = w1[t * 3], wy = w1[t * 3 + 1], wz = w1[t * 3 + 2];
    float mean = (wx * S[0] + wy * S[1] + wz * S[2]) * Rinv;
    float e2 = (wx * wx * S[3] + wy * wy * S[4] + wz * wz * S[5] +
                2.f * (wx * wy * S[6] + wx * wz * S[7] + wy * wz * S[8])) * Rinv;
    float var = e2 - mean * mean;
    float a = g[t] * rsqrtf(var + BN_EPS);
    scsh[t] = a;
    scsh[64 + t] = bb[t] - mean * a;
}

// ============ KNN all 6 tasks in one launch (wave per query) ============
__global__ void knn_all_kernel(const float* __restrict__ x, int Nstride,
                               int* __restrict__ iA, int* __restrict__ iB,
                               int* __restrict__ iC, int* __restrict__ iD,
                               int* __restrict__ iE, int* __restrict__ iF) {
    int b = blockIdx.y;
    int bx = blockIdx.x;
    int M, N; int* out; int qbase;
    if (bx < 256)      { M = 1024; N = 4096; out = iA; qbase = bx * 4; }
    else if (bx < 272) { M = 64;   N = 1024; out = iB; qbase = (bx - 256) * 4; }
    else if (bx < 336) { M = 256;  N = 1024; out = iC; qbase = (bx - 272) * 4; }
    else if (bx < 352) { M = 64;   N = 256;  out = iD; qbase = (bx - 336) * 4; }
    else if (bx < 384) { M = 128;  N = 256;  out = iE; qbase = (bx - 352) * 4; }
    else               { M = 64;   N = 128;  out = iF; qbase = (bx - 384) * 4; }
    int wave = threadIdx.x >> 6;
    int lane = threadIdx.x & 63;
    int q = qbase + wave;
    const float* xb = x + (size_t)b * 3 * Nstride;
    float qx = xb[q], qy = xb[Nstride + q], qz = xb[2 * Nstride + q];
    float qq = qx * qx + qy * qy + qz * qz;

    float ld = 3.4e38f; int li = 0;
    float w = 3.4e38f;
    for (int j0 = 0; j0 < N; j0 += 64) {
        int j = j0 + lane;
        float cxv = xb[j], cyv = xb[Nstride + j], czv = xb[2 * Nstride + j];
        float cn = cxv * cxv + cyv * cyv + czv * czv;
        float d2 = qq + cn - 2.f * (qx * cxv + qy * cyv + qz * czv);
        unsigned long long msk = __ballot(d2 < w);
        while (msk) {
            int src = (int)__ffsll(msk) - 1;
            float d = __shfl(d2, src);
            int idx = j0 + src;
            if (d < w) {
                float up_d = __shfl_up(ld, 1);
                int   up_i = __shfl_up(li, 1);
                bool c  = d < ld;
                bool cp = (lane != 0) && (d < up_d);
                ld = c ? (cp ? up_d : d) : ld;
                li = c ? (cp ? up_i : idx) : li;
                w = __shfl(ld, 19);
            }
            msk &= msk - 1;
        }
    }
    if (lane < KNN) out[((size_t)b * M + q) * KNN + lane] = li;
}

// ============ stage-1 pool: gather coords, dot with w1, min/max, bn+lrelu ====
__global__ void pool1_kernel(const float* __restrict__ x, int N, const int* __restrict__ idxA,
                             const float* __restrict__ w1, const float* __restrict__ scsh,
                             float* __restrict__ out, int M) {
    int c = threadIdx.x;                    // 64
    int m = blockIdx.x * 4 + threadIdx.y;   // blockDim (64,4)
    int b = blockIdx.y;
    const float* xb = x + (size_t)b * 3 * N;
    const int* ip = idxA + ((size_t)b * M + m) * KNN;
    float wx = w1[c * 3], wy = w1[c * 3 + 1], wz = w1[c * 3 + 2];
    float mx = -3.4e38f, mn = 3.4e38f;
#pragma unroll
    for (int k = 0; k < KNN; ++k) {
        int j = ip[k];
        float d = wx * xb[j] + wy * xb[N + j] + wz * xb[2 * N + j];
        mx = fmaxf(mx, d); mn = fminf(mn, d);
    }
    float a = scsh[c];
    float v = a * (a >= 0.f ? mx : mn) + scsh[64 + c];
    out[((size_t)b * M + m) * 64 + c] = v >= 0.f ? v : 0.2f * v;
}

// ============ generic gather pool; MODE1 applies bn+lrelu via min/max =======
template <int MODE>
__global__ void pool_kernel(const float* __restrict__ f, const int* __restrict__ idx,
                            float* __restrict__ out, int M, int Nf, int C,
                            int out_stride, int out_off, const float* __restrict__ scsh) {
    int c = threadIdx.x;                               // blockDim.x == C
    int m = blockIdx.x * blockDim.y + threadIdx.y;
    int b = blockIdx.y;
    const int* ip = idx + ((size_t)b * M + m) * KNN;
    const float* fb = f + (size_t)b * Nf * C;
    float mx = -3.4e38f, mn = 3.4e38f;
#pragma unroll
    for (int k = 0; k < KNN; ++k) {
        int j = ip[k];
        float v = fb[(size_t)j * C + c];
        mx = fmaxf(mx, v);
        if (MODE) mn = fminf(mn, v);
    }
    float v;
    if (MODE) {
        float a = scsh[c];
        v = a * (a >= 0.f ? mx : mn) + scsh[C + c];
        v = v >= 0.f ? v : 0.2f * v;
    } else v = mx;
    out[((size_t)b * M + m) * out_stride + out_off + c] = v;
}

// ============ 64x64-tile GEMM, 4x4/thread, optional BN-stats epilogue =======
// C[m,n] = sum_k A[m,k] * W[n,k]; M,N multiples of 64, K multiple of 16.
template <bool STATS>
__global__ void gemm64_kernel(const float* __restrict__ A, const float* __restrict__ W,
                              float* __restrict__ Cout, int M, int N, int K,
                              float* __restrict__ part /*[M/64][2][N]*/) {
    __shared__ float As[16][65], Ws[16][65];
    int t = threadIdx.x;
    int tx = t & 15, ty = t >> 4;
    int bm = blockIdx.x, bn = blockIdx.y;
    const float* Ab = A + (size_t)bm * 64 * K;
    const float* Wb = W + (size_t)bn * 64 * K;
    float acc[4][4] = {};
    for (int k0 = 0; k0 < K; k0 += 16) {
#pragma unroll
        for (int r = 0; r < 4; ++r) {
            int row = (t >> 4) + r * 16;
            As[t & 15][row] = Ab[(size_t)row * K + k0 + (t & 15)];
            Ws[t & 15][row] = Wb[(size_t)row * K + k0 + (t & 15)];
        }
        __syncthreads();
#pragma unroll
        for (int kk = 0; kk < 16; ++kk) {
            float a4[4], w4[4];
#pragma unroll
            for (int i = 0; i < 4; ++i) a4[i] = As[kk][ty * 4 + i];
#pragma unroll
            for (int j = 0; j < 4; ++j) w4[j] = Ws[kk][tx * 4 + j];
#pragma unroll
            for (int i = 0; i < 4; ++i)
#pragma unroll
                for (int j = 0; j < 4; ++j) acc[i][j] += a4[i] * w4[j];
        }
        __syncthreads();
    }
#pragma unroll
    for (int i = 0; i < 4; ++i) {
        float4 v = make_float4(acc[i][0], acc[i][1], acc[i][2], acc[i][3]);
        *(float4*)&Cout[(size_t)(bm * 64 + ty * 4 + i) * N + bn * 64 + tx * 4] = v;
    }
    if (STATS) {
        __shared__ float2 sred[16][64];
#pragma unroll
        for (int j = 0; j < 4; ++j) {
            float s = 0.f, q = 0.f;
#pragma unroll
            for (int i = 0; i < 4; ++i) { s += acc[i][j]; q += acc[i][j] * acc[i][j]; }
            sred[ty][tx * 4 + j] = make_float2(s, q);
        }
        __syncthreads();
        if (t < 64) {
            float s = 0.f, q = 0.f;
#pragma unroll
            for (int r = 0; r < 16; ++r) { s += sred[r][t].x; q += sred[r][t].y; }
            part[(size_t)bm * 2 * N + bn * 64 + t] = s;
            part[(size_t)bm * 2 * N + N + bn * 64 + t] = q;
        }
    }
}

// partials -> scale/shift
__global__ void bn_finalize_kernel(const float* __restrict__ part, int nparts, int C, int R,
                                   const float* __restrict__ g, const float* __restrict__ bb,
                                   float* __restrict__ scsh) {
    int c = blockIdx.x;
    int t = threadIdx.x;   // 256
    float s = 0.f, q = 0.f;
    for (int k = t; k < nparts; k += 256) {
        s += part[(size_t)k * 2 * C + c];
        q += part[(size_t)k * 2 * C + C + c];
    }
#pragma unroll
    for (int o = 32; o; o >>= 1) { s += __shfl_down(s, o); q += __shfl_down(q, o); }
    __shared__ float2 red[4];
    if ((t & 63) == 0) red[t >> 6] = make_float2(s, q);
    __syncthreads();
    if (t == 0) {
        s = red[0].x + red[1].x + red[2].x + red[3].x;
        q = red[0].y + red[1].y + red[2].y + red[3].y;
        float mean = s / (float)R;
        float var = q / (float)R - mean * mean;
        float a = g[c] * rsqrtf(var + BN_EPS);
        scsh[c] = a;
        scsh[C + c] = bb[c] - mean * a;
    }
}

// ============ global max+mean pool with fused bn+lrelu ============
__global__ void global_pool_bn_kernel(const float* __restrict__ h,
                                      const float* __restrict__ scsh,
                                      float* __restrict__ out) {
    int c = blockIdx.x * 256 + threadIdx.x;   // C=1024
    int b = blockIdx.y;
    const float* hb = h + (size_t)b * 64 * 1024;
    float a = scsh[c], sh = scsh[1024 + c];
    float mx = -3.4e38f, s = 0.f;
    for (int r = 0; r < 64; ++r) {
        float v = a * hb[r * 1024 + c] + sh;
        v = v >= 0.f ? v : 0.2f * v;
        mx = fmaxf(mx, v); s += v;
    }
    out[b * 2048 + c] = mx;
    out[b * 2048 + 1024 + c] = s * (1.f / 64.f);
}

// ============ small GEMM for the head (M=16) ============
__global__ void gemm_tn(const float* __restrict__ A, const float* __restrict__ W,
                        const float* __restrict__ bias, float* __restrict__ Cout,
                        int M, int N, int K) {
    __shared__ float As[16][17], Ws[16][17];
    int tx = threadIdx.x, ty = threadIdx.y;
    int row = blockIdx.x * 16 + ty;
    int col = blockIdx.y * 16 + tx;
    float acc = 0.f;
    for (int k0 = 0; k0 < K; k0 += 16) {
        int ar = blockIdx.x * 16 + ty;
        As[ty][tx] = (ar < M && (k0 + tx) < K) ? A[(size_t)ar * K + k0 + tx] : 0.f;
        int wr = blockIdx.y * 16 + ty;
        Ws[ty][tx] = (wr < N && (k0 + tx) < K) ? W[(size_t)wr * K + k0 + tx] : 0.f;
        __syncthreads();
#pragma unroll
        for (int kk = 0; kk < 16; ++kk) acc += As[ty][kk] * Ws[tx][kk];
        __syncthreads();
    }
    if (row < M && col < N) {
        if (bias) acc += bias[col];
        Cout[(size_t)row * N + col] = acc;
    }
}

// BN over R=16 rows, stats+apply in one kernel
__global__ void small_bn_kernel(float* __restrict__ y, const float* __restrict__ g,
                                const float* __restrict__ bb, int C) {
    int c = blockIdx.x * 64 + threadIdx.x;
    if (c >= C) return;
    float vals[16];
    float s = 0.f, q = 0.f;
#pragma unroll
    for (int r = 0; r < 16; ++r) {
        float v = y[r * C + c];
        vals[r] = v; s += v; q += v * v;
    }
    float mean = s * (1.f / 16.f);
    float var = q * (1.f / 16.f) - mean * mean;
    float a = g[c] * rsqrtf(var + BN_EPS);
    float sh = bb[c] - mean * a;
#pragma unroll
    for (int r = 0; r < 16; ++r) {
        float v = a * vals[r] + sh;
        y[r * C + c] = v >= 0.f ? v : 0.2f * v;
    }
}

extern "C" void kernel_launch(void* const* d_in, const int* in_sizes, int n_in,
                              void* d_out, int out_size, void* d_ws, size_t ws_size,
                              hipStream_t stream) {
    const int B = 16, N = 4096;
    const float* x   = (const float*)d_in[0];
    const float* w1  = (const float*)d_in[1];
    const float* g1  = (const float*)d_in[2];
    const float* b1  = (const float*)d_in[3];
    const float* w2  = (const float*)d_in[4];
    const float* g2  = (const float*)d_in[5];
    const float* b2  = (const float*)d_in[6];
    const float* w3  = (const float*)d_in[7];
    const float* g3  = (const float*)d_in[8];
    const float* b3  = (const float*)d_in[9];
    const float* w4  = (const float*)d_in[10];
    const float* g4  = (const float*)d_in[11];
    const float* b4  = (const float*)d_in[12];
    const float* w5  = (const float*)d_in[13];
    const float* g5  = (const float*)d_in[14];
    const float* b5  = (const float*)d_in[15];
    const float* l1w = (const float*)d_in[16];
    const float* g6  = (const float*)d_in[17];
    const float* b6  = (const float*)d_in[18];
    const float* l2w = (const float*)d_in[19];
    const float* l2b = (const float*)d_in[20];
    const float* g7  = (const float*)d_in[21];
    const float* b7  = (const float*)d_in[22];
    const float* l3w = (const float*)d_in[23];
    const float* l3b = (const float*)d_in[24];
    float* outp = (float*)d_out;

    char* ws = (char*)d_ws;
    size_t off = 0;
    auto alloc = [&](size_t bytes) -> void* {
        void* p = ws + off;
        off += (bytes + 255) & ~(size_t)255;
        return p;
    };
    float* f1p   = (float*)alloc((size_t)B * 1024 * 64 * 4);
    float* f2pre = (float*)alloc((size_t)B * 1024 * 64 * 4);
    float* f2p   = (float*)alloc((size_t)B * 256 * 64 * 4);
    float* f3pre = (float*)alloc((size_t)B * 256 * 128 * 4);
    float* f3p   = (float*)alloc((size_t)B * 128 * 128 * 4);
    float* f4pre = (float*)alloc((size_t)B * 128 * 256 * 4);
    float* hcat  = (float*)alloc((size_t)B * 64 * 512 * 4);
    float* h5pre = (float*)alloc((size_t)B * 64 * 1024 * 4);
    float* hg    = (float*)alloc((size_t)B * 2048 * 4);
    float* h6    = (float*)alloc((size_t)B * 512 * 4);
    float* h7    = (float*)alloc((size_t)B * 256 * 4);
    int* idxA = (int*)alloc((size_t)B * 1024 * KNN * 4);
    int* idxB = (int*)alloc((size_t)B * 64 * KNN * 4);
    int* idxC = (int*)alloc((size_t)B * 256 * KNN * 4);
    int* idxD = (int*)alloc((size_t)B * 64 * KNN * 4);
    int* idxE = (int*)alloc((size_t)B * 128 * KNN * 4);
    int* idxF = (int*)alloc((size_t)B * 64 * KNN * 4);
    float* mom   = (float*)alloc((size_t)B * 9 * 4);
    float* part2 = (float*)alloc((size_t)256 * 2 * 64 * 4);
    float* part3 = (float*)alloc((size_t)64 * 2 * 128 * 4);
    float* part4 = (float*)alloc((size_t)32 * 2 * 256 * 4);
    float* part5 = (float*)alloc((size_t)16 * 2 * 1024 * 4);
    float* sc1 = (float*)alloc(2 * 64 * 4);
    float* sc2 = (float*)alloc(2 * 64 * 4);
    float* sc3 = (float*)alloc(2 * 128 * 4);
    float* sc4 = (float*)alloc(2 * 256 * 4);
    float* sc5 = (float*)alloc(2 * 1024 * 4);

    // ---- KNN (all 6 tasks) + stage-1 moments
    knn_all_kernel<<<dim3(400, B), 256, 0, stream>>>(x, N, idxA, idxB, idxC, idxD, idxE, idxF);
    moments3_kernel<<<dim3(B), 256, 0, stream>>>(x, N, mom);
    finalize1_kernel<<<dim3(1), 64, 0, stream>>>(mom, w1, g1, b1, sc1, 1.f / (B * N), B);

    // ---- stage 1 pool (computes conv1 features on the fly)
    pool1_kernel<<<dim3(256, B), dim3(64, 4), 0, stream>>>(x, N, idxA, w1, sc1, f1p, 1024);
    pool_kernel<0><<<dim3(16, B), dim3(64, 4), 0, stream>>>(f1p, idxB, hcat, 64, 1024, 64, 512, 0, nullptr);

    // ---- stage 2
    gemm64_kernel<true><<<dim3(256, 1), 256, 0, stream>>>(f1p, w2, f2pre, B * 1024, 64, 64, part2);
    bn_finalize_kernel<<<dim3(64), 256, 0, stream>>>(part2, 256, 64, B * 1024, g2, b2, sc2);
    pool_kernel<1><<<dim3(64, B), dim3(64, 4), 0, stream>>>(f2pre, idxC, f2p, 256, 1024, 64, 64, 0, sc2);
    pool_kernel<0><<<dim3(16, B), dim3(64, 4), 0, stream>>>(f2p, idxD, hcat, 64, 256, 64, 512, 64, nullptr);

    // ---- stage 3
    gemm64_kernel<true><<<dim3(64, 2), 256, 0, stream>>>(f2p, w3, f3pre, B * 256, 128, 64, part3);
    bn_finalize_kernel<<<dim3(128), 256, 0, stream>>>(part3, 64, 128, B * 256, g3, b3, sc3);
    pool_kernel<1><<<dim3(64, B), dim3(128, 2), 0, stream>>>(f3pre, idxE, f3p, 128, 256, 128, 128, 0, sc3);
    pool_kernel<0><<<dim3(32, B), dim3(128, 2), 0, stream>>>(f3p, idxF, hcat, 64, 128, 128, 512, 128, nullptr);

    // ---- stage 4
    gemm64_kernel<true><<<dim3(32, 4), 256, 0, stream>>>(f3p, w4, f4pre, B * 128, 256, 128, part4);
    bn_finalize_kernel<<<dim3(256), 256, 0, stream>>>(part4, 32, 256, B * 128, g4, b4, sc4);
    pool_kernel<1><<<dim3(64, B), dim3(256, 1), 0, stream>>>(f4pre, idxF, hcat, 64, 128, 256, 512, 256, sc4);

    // ---- stage 5
    gemm64_kernel<true><<<dim3(16, 16), 256, 0, stream>>>(hcat, w5, h5pre, B * 64, 1024, 512, part5);
    bn_finalize_kernel<<<dim3(1024), 256, 0, stream>>>(part5, 16, 1024, B * 64, g5, b5, sc5);
    global_pool_bn_kernel<<<dim3(4, B), 256, 0, stream>>>(h5pre, sc5, hg);

    // ---- head
    gemm_tn<<<dim3(1, 32), dim3(16, 16), 0, stream>>>(hg, l1w, nullptr, h6, B, 512, 2048);
    small_bn_kernel<<<dim3(8), 64, 0, stream>>>(h6, g6, b6, 512);
    gemm_tn<<<dim3(1, 16), dim3(16, 16), 0, stream>>>(h6, l2w, l2b, h7, B, 256, 512);
    small_bn_kernel<<<dim3(4), 64, 0, stream>>>(h7, g7, b7, 256);
    gemm_tn<<<dim3(1, 3), dim3(16, 16), 0, stream>>>(h7, l3w, l3b, outp, B, 40, 256);
}

// Round 5
// 374.650 us; speedup vs baseline: 28.0831x; 1.0109x over previous
//
#include <hip/hip_runtime.h>

#define BN_EPS 1e-5f
#define KNN 20

static inline int ceildiv(int a, int b) { return (a + b - 1) / b; }

// ============ stage-1 moments (Σp, Σppᵀ) + per-point squared norms ============
__global__ void moments3_kernel(const float* __restrict__ x, int N,
                                float* __restrict__ part /*[B][9]*/,
                                float* __restrict__ norms /*[B][N]*/) {
    int b = blockIdx.x;
    int t = threadIdx.x;   // 256
    const float* xb = x + (size_t)b * 3 * N;
    float m[9] = {0, 0, 0, 0, 0, 0, 0, 0, 0};
    for (int n = t; n < N; n += 256) {
        float px = xb[n], py = xb[N + n], pz = xb[2 * N + n];
        norms[(size_t)b * N + n] = px * px + py * py + pz * pz;
        m[0] += px; m[1] += py; m[2] += pz;
        m[3] += px * px; m[4] += py * py; m[5] += pz * pz;
        m[6] += px * py; m[7] += px * pz; m[8] += py * pz;
    }
#pragma unroll
    for (int o = 32; o; o >>= 1)
#pragma unroll
        for (int i = 0; i < 9; ++i) m[i] += __shfl_down(m[i], o);
    __shared__ float red[4][9];
    if ((t & 63) == 0)
#pragma unroll
        for (int i = 0; i < 9; ++i) red[t >> 6][i] = m[i];
    __syncthreads();
    if (t == 0) {
#pragma unroll
        for (int i = 0; i < 9; ++i)
            part[b * 9 + i] = red[0][i] + red[1][i] + red[2][i] + red[3][i];
    }
}

// ============ KNN all 6 tasks in one launch (wave per query) ============
// Lane-distributed sorted list (lane k = k-th best). Stale-w batching: the
// 20th-best w is refreshed once per 64-candidate tile, survivors are inserted
// unconditionally (sorted-list invariant keeps the top-20 prefix exact).
__global__ void knn_all_kernel(const float* __restrict__ x, const float* __restrict__ norms,
                               int Nstride,
                               int* __restrict__ iA, int* __restrict__ iB,
                               int* __restrict__ iC, int* __restrict__ iD,
                               int* __restrict__ iE, int* __restrict__ iF) {
    int b = blockIdx.y;
    int bx = blockIdx.x;
    int M, N; int* out; int qbase;
    if (bx < 256)      { M = 1024; N = 4096; out = iA; qbase = bx * 4; }
    else if (bx < 272) { M = 64;   N = 1024; out = iB; qbase = (bx - 256) * 4; }
    else if (bx < 336) { M = 256;  N = 1024; out = iC; qbase = (bx - 272) * 4; }
    else if (bx < 352) { M = 64;   N = 256;  out = iD; qbase = (bx - 336) * 4; }
    else if (bx < 384) { M = 128;  N = 256;  out = iE; qbase = (bx - 352) * 4; }
    else               { M = 64;   N = 128;  out = iF; qbase = (bx - 384) * 4; }
    int wave = threadIdx.x >> 6;
    int lane = threadIdx.x & 63;
    int q = qbase + wave;
    const float* xb = x + (size_t)b * 3 * Nstride;
    const float* nb = norms + (size_t)b * Nstride;
    float qx = xb[q], qy = xb[Nstride + q], qz = xb[2 * Nstride + q];
    float qq = nb[q];

    float ld = 3.4e38f; int li = 0;
    float w = 3.4e38f;
    for (int j0 = 0; j0 < N; j0 += 64) {
        int j = j0 + lane;
        float cxv = xb[j], cyv = xb[Nstride + j], czv = xb[2 * Nstride + j];
        float d2 = qq + nb[j] - 2.f * (qx * cxv + qy * cyv + qz * czv);
        unsigned long long msk = __ballot(d2 < w);
        while (msk) {
            int src = (int)__ffsll(msk) - 1;
            float d = __shfl(d2, src);
            int idx = j0 + src;
            float up_d = __shfl_up(ld, 1);
            int   up_i = __shfl_up(li, 1);
            bool c  = d < ld;
            bool cp = (lane != 0) && (d < up_d);
            ld = c ? (cp ? up_d : d) : ld;
            li = c ? (cp ? up_i : idx) : li;
            msk &= msk - 1;
        }
        w = __shfl(ld, 19);
    }
    if (lane < KNN) out[((size_t)b * M + q) * KNN + lane] = li;
}

// ============ stage-1 pool: fused finalize1 + gather + dot + bn + lrelu ======
__global__ void pool1_kernel(const float* __restrict__ x, int N, const int* __restrict__ idxA,
                             const float* __restrict__ w1, const float* __restrict__ mom,
                             const float* __restrict__ g, const float* __restrict__ bb,
                             float Rinv, int Bn, float* __restrict__ out, int M) {
    __shared__ float S[9];
    __shared__ float sca[64], shb[64];
    int c = threadIdx.x;                    // 64
    int tid = threadIdx.y * 64 + c;
    if (tid < 9) {
        float s = 0.f;
        for (int bi = 0; bi < Bn; ++bi) s += mom[bi * 9 + tid];
        S[tid] = s;
    }
    __syncthreads();
    if (tid < 64) {
        float wx = w1[tid * 3], wy = w1[tid * 3 + 1], wz = w1[tid * 3 + 2];
        float mean = (wx * S[0] + wy * S[1] + wz * S[2]) * Rinv;
        float e2 = (wx * wx * S[3] + wy * wy * S[4] + wz * wz * S[5] +
                    2.f * (wx * wy * S[6] + wx * wz * S[7] + wy * wz * S[8])) * Rinv;
        float var = e2 - mean * mean;
        float a = g[tid] * rsqrtf(var + BN_EPS);
        sca[tid] = a;
        shb[tid] = bb[tid] - mean * a;
    }
    __syncthreads();
    int m = blockIdx.x * 4 + threadIdx.y;
    int b = blockIdx.y;
    const float* xb = x + (size_t)b * 3 * N;
    const int* ip = idxA + ((size_t)b * M + m) * KNN;
    float wx = w1[c * 3], wy = w1[c * 3 + 1], wz = w1[c * 3 + 2];
    float mx = -3.4e38f, mn = 3.4e38f;
#pragma unroll
    for (int k = 0; k < KNN; ++k) {
        int j = ip[k];
        float d = wx * xb[j] + wy * xb[N + j] + wz * xb[2 * N + j];
        mx = fmaxf(mx, d); mn = fminf(mn, d);
    }
    float a = sca[c];
    float v = a * (a >= 0.f ? mx : mn) + shb[c];
    out[((size_t)b * M + m) * 64 + c] = v >= 0.f ? v : 0.2f * v;
}

// ============ generic gather pool; MODE1 applies bn+lrelu via min/max =======
template <int MODE>
__global__ void pool_kernel(const float* __restrict__ f, const int* __restrict__ idx,
                            float* __restrict__ out, int M, int Nf, int C,
                            int out_stride, int out_off, const float* __restrict__ scsh) {
    int c = threadIdx.x;                               // blockDim.x == C
    int m = blockIdx.x * blockDim.y + threadIdx.y;
    int b = blockIdx.y;
    const int* ip = idx + ((size_t)b * M + m) * KNN;
    const float* fb = f + (size_t)b * Nf * C;
    float mx = -3.4e38f, mn = 3.4e38f;
#pragma unroll
    for (int k = 0; k < KNN; ++k) {
        int j = ip[k];
        float v = fb[(size_t)j * C + c];
        mx = fmaxf(mx, v);
        if (MODE) mn = fminf(mn, v);
    }
    float v;
    if (MODE) {
        float a = scsh[c];
        v = a * (a >= 0.f ? mx : mn) + scsh[C + c];
        v = v >= 0.f ? v : 0.2f * v;
    } else v = mx;
    out[((size_t)b * M + m) * out_stride + out_off + c] = v;
}

// ============ 64x64-tile GEMM, 4x4/thread, optional BN-stats epilogue =======
template <bool STATS>
__global__ void gemm64_kernel(const float* __restrict__ A, const float* __restrict__ W,
                              float* __restrict__ Cout, int M, int N, int K,
                              float* __restrict__ part /*[M/64][2][N]*/) {
    __shared__ float As[16][65], Ws[16][65];
    int t = threadIdx.x;
    int tx = t & 15, ty = t >> 4;
    int bm = blockIdx.x, bn = blockIdx.y;
    const float* Ab = A + (size_t)bm * 64 * K;
    const float* Wb = W + (size_t)bn * 64 * K;
    float acc[4][4] = {};
    for (int k0 = 0; k0 < K; k0 += 16) {
#pragma unroll
        for (int r = 0; r < 4; ++r) {
            int row = (t >> 4) + r * 16;
            As[t & 15][row] = Ab[(size_t)row * K + k0 + (t & 15)];
            Ws[t & 15][row] = Wb[(size_t)row * K + k0 + (t & 15)];
        }
        __syncthreads();
#pragma unroll
        for (int kk = 0; kk < 16; ++kk) {
            float a4[4], w4[4];
#pragma unroll
            for (int i = 0; i < 4; ++i) a4[i] = As[kk][ty * 4 + i];
#pragma unroll
            for (int j = 0; j < 4; ++j) w4[j] = Ws[kk][tx * 4 + j];
#pragma unroll
            for (int i = 0; i < 4; ++i)
#pragma unroll
                for (int j = 0; j < 4; ++j) acc[i][j] += a4[i] * w4[j];
        }
        __syncthreads();
    }
#pragma unroll
    for (int i = 0; i < 4; ++i) {
        float4 v = make_float4(acc[i][0], acc[i][1], acc[i][2], acc[i][3]);
        *(float4*)&Cout[(size_t)(bm * 64 + ty * 4 + i) * N + bn * 64 + tx * 4] = v;
    }
    if (STATS) {
        __shared__ float2 sred[16][64];
#pragma unroll
        for (int j = 0; j < 4; ++j) {
            float s = 0.f, q = 0.f;
#pragma unroll
            for (int i = 0; i < 4; ++i) { s += acc[i][j]; q += acc[i][j] * acc[i][j]; }
            sred[ty][tx * 4 + j] = make_float2(s, q);
        }
        __syncthreads();
        if (t < 64) {
            float s = 0.f, q = 0.f;
#pragma unroll
            for (int r = 0; r < 16; ++r) { s += sred[r][t].x; q += sred[r][t].y; }
            part[(size_t)bm * 2 * N + bn * 64 + t] = s;
            part[(size_t)bm * 2 * N + N + bn * 64 + t] = q;
        }
    }
}

// partials -> scale/shift
__global__ void bn_finalize_kernel(const float* __restrict__ part, int nparts, int C, int R,
                                   const float* __restrict__ g, const float* __restrict__ bb,
                                   float* __restrict__ scsh) {
    int c = blockIdx.x;
    int t = threadIdx.x;   // 256
    float s = 0.f, q = 0.f;
    for (int k = t; k < nparts; k += 256) {
        s += part[(size_t)k * 2 * C + c];
        q += part[(size_t)k * 2 * C + C + c];
    }
#pragma unroll
    for (int o = 32; o; o >>= 1) { s += __shfl_down(s, o); q += __shfl_down(q, o); }
    __shared__ float2 red[4];
    if ((t & 63) == 0) red[t >> 6] = make_float2(s, q);
    __syncthreads();
    if (t == 0) {
        s = red[0].x + red[1].x + red[2].x + red[3].x;
        q = red[0].y + red[1].y + red[2].y + red[3].y;
        float mean = s / (float)R;
        float var = q / (float)R - mean * mean;
        float a = g[c] * rsqrtf(var + BN_EPS);
        scsh[c] = a;
        scsh[C + c] = bb[c] - mean * a;
    }
}

// ============ global max+mean pool with fused bn+lrelu ============
__global__ void global_pool_bn_kernel(const float* __restrict__ h,
                                      const float* __restrict__ scsh,
                                      float* __restrict__ out) {
    int c = blockIdx.x * 256 + threadIdx.x;   // C=1024
    int b = blockIdx.y;
    const float* hb = h + (size_t)b * 64 * 1024;
    float a = scsh[c], sh = scsh[1024 + c];
    float mx = -3.4e38f, s = 0.f;
    for (int r = 0; r < 64; ++r) {
        float v = a * hb[r * 1024 + c] + sh;
        v = v >= 0.f ? v : 0.2f * v;
        mx = fmaxf(mx, v); s += v;
    }
    out[b * 2048 + c] = mx;
    out[b * 2048 + 1024 + c] = s * (1.f / 64.f);
}

// ============ head GEMM: one thread per output, float4 dot over K ============
__global__ void head_gemm_kernel(const float* __restrict__ A, const float* __restrict__ W,
                                 const float* __restrict__ bias, float* __restrict__ out,
                                 int N, int K) {
    int n = blockIdx.x * 64 + threadIdx.x;
    int m = blockIdx.y;
    if (n >= N) return;
    const float4* a4 = (const float4*)(A + (size_t)m * K);
    const float4* w4 = (const float4*)(W + (size_t)n * K);
    int K4 = K >> 2;
    float acc0 = 0.f, acc1 = 0.f, acc2 = 0.f, acc3 = 0.f;
    for (int k = 0; k < K4; ++k) {
        float4 a = a4[k], w = w4[k];
        acc0 = fmaf(a.x, w.x, acc0);
        acc1 = fmaf(a.y, w.y, acc1);
        acc2 = fmaf(a.z, w.z, acc2);
        acc3 = fmaf(a.w, w.w, acc3);
    }
    float r = (acc0 + acc1) + (acc2 + acc3);
    if (bias) r += bias[n];
    out[(size_t)m * N + n] = r;
}

// BN over R=16 rows, stats+apply in one kernel
__global__ void small_bn_kernel(float* __restrict__ y, const float* __restrict__ g,
                                const float* __restrict__ bb, int C) {
    int c = blockIdx.x * 64 + threadIdx.x;
    if (c >= C) return;
    float vals[16];
    float s = 0.f, q = 0.f;
#pragma unroll
    for (int r = 0; r < 16; ++r) {
        float v = y[r * C + c];
        vals[r] = v; s += v; q += v * v;
    }
    float mean = s * (1.f / 16.f);
    float var = q * (1.f / 16.f) - mean * mean;
    float a = g[c] * rsqrtf(var + BN_EPS);
    float sh = bb[c] - mean * a;
#pragma unroll
    for (int r = 0; r < 16; ++r) {
        float v = a * vals[r] + sh;
        y[r * C + c] = v >= 0.f ? v : 0.2f * v;
    }
}

extern "C" void kernel_launch(void* const* d_in, const int* in_sizes, int n_in,
                              void* d_out, int out_size, void* d_ws, size_t ws_size,
                              hipStream_t stream) {
    const int B = 16, N = 4096;
    const float* x   = (const float*)d_in[0];
    const float* w1  = (const float*)d_in[1];
    const float* g1  = (const float*)d_in[2];
    const float* b1  = (const float*)d_in[3];
    const float* w2  = (const float*)d_in[4];
    const float* g2  = (const float*)d_in[5];
    const float* b2  = (const float*)d_in[6];
    const float* w3  = (const float*)d_in[7];
    const float* g3  = (const float*)d_in[8];
    const float* b3  = (const float*)d_in[9];
    const float* w4  = (const float*)d_in[10];
    const float* g4  = (const float*)d_in[11];
    const float* b4  = (const float*)d_in[12];
    const float* w5  = (const float*)d_in[13];
    const float* g5  = (const float*)d_in[14];
    const float* b5  = (const float*)d_in[15];
    const float* l1w = (const float*)d_in[16];
    const float* g6  = (const float*)d_in[17];
    const float* b6  = (const float*)d_in[18];
    const float* l2w = (const float*)d_in[19];
    const float* l2b = (const float*)d_in[20];
    const float* g7  = (const float*)d_in[21];
    const float* b7  = (const float*)d_in[22];
    const float* l3w = (const float*)d_in[23];
    const float* l3b = (const float*)d_in[24];
    float* outp = (float*)d_out;

    char* ws = (char*)d_ws;
    size_t off = 0;
    auto alloc = [&](size_t bytes) -> void* {
        void* p = ws + off;
        off += (bytes + 255) & ~(size_t)255;
        return p;
    };
    float* f1p   = (float*)alloc((size_t)B * 1024 * 64 * 4);
    float* f2pre = (float*)alloc((size_t)B * 1024 * 64 * 4);
    float* f2p   = (float*)alloc((size_t)B * 256 * 64 * 4);
    float* f3pre = (float*)alloc((size_t)B * 256 * 128 * 4);
    float* f3p   = (float*)alloc((size_t)B * 128 * 128 * 4);
    float* f4pre = (float*)alloc((size_t)B * 128 * 256 * 4);
    float* hcat  = (float*)alloc((size_t)B * 64 * 512 * 4);
    float* h5pre = (float*)alloc((size_t)B * 64 * 1024 * 4);
    float* hg    = (float*)alloc((size_t)B * 2048 * 4);
    float* h6    = (float*)alloc((size_t)B * 512 * 4);
    float* h7    = (float*)alloc((size_t)B * 256 * 4);
    int* idxA = (int*)alloc((size_t)B * 1024 * KNN * 4);
    int* idxB = (int*)alloc((size_t)B * 64 * KNN * 4);
    int* idxC = (int*)alloc((size_t)B * 256 * KNN * 4);
    int* idxD = (int*)alloc((size_t)B * 64 * KNN * 4);
    int* idxE = (int*)alloc((size_t)B * 128 * KNN * 4);
    int* idxF = (int*)alloc((size_t)B * 64 * KNN * 4);
    float* mom   = (float*)alloc((size_t)B * 9 * 4);
    float* norms = (float*)alloc((size_t)B * N * 4);
    float* part2 = (float*)alloc((size_t)256 * 2 * 64 * 4);
    float* part3 = (float*)alloc((size_t)64 * 2 * 128 * 4);
    float* part4 = (float*)alloc((size_t)32 * 2 * 256 * 4);
    float* part5 = (float*)alloc((size_t)16 * 2 * 1024 * 4);
    float* sc2 = (float*)alloc(2 * 64 * 4);
    float* sc3 = (float*)alloc(2 * 128 * 4);
    float* sc4 = (float*)alloc(2 * 256 * 4);
    float* sc5 = (float*)alloc(2 * 1024 * 4);

    // ---- moments + norms, then KNN (all 6 tasks)
    moments3_kernel<<<dim3(B), 256, 0, stream>>>(x, N, mom, norms);
    knn_all_kernel<<<dim3(400, B), 256, 0, stream>>>(x, norms, N, idxA, idxB, idxC, idxD, idxE, idxF);

    // ---- stage 1 pool (conv1 features on the fly; finalize fused in-block)
    pool1_kernel<<<dim3(256, B), dim3(64, 4), 0, stream>>>(x, N, idxA, w1, mom, g1, b1,
                                                           1.f / (B * N), B, f1p, 1024);
    pool_kernel<0><<<dim3(16, B), dim3(64, 4), 0, stream>>>(f1p, idxB, hcat, 64, 1024, 64, 512, 0, nullptr);

    // ---- stage 2
    gemm64_kernel<true><<<dim3(256, 1), 256, 0, stream>>>(f1p, w2, f2pre, B * 1024, 64, 64, part2);
    bn_finalize_kernel<<<dim3(64), 256, 0, stream>>>(part2, 256, 64, B * 1024, g2, b2, sc2);
    pool_kernel<1><<<dim3(64, B), dim3(64, 4), 0, stream>>>(f2pre, idxC, f2p, 256, 1024, 64, 64, 0, sc2);
    pool_kernel<0><<<dim3(16, B), dim3(64, 4), 0, stream>>>(f2p, idxD, hcat, 64, 256, 64, 512, 64, nullptr);

    // ---- stage 3
    gemm64_kernel<true><<<dim3(64, 2), 256, 0, stream>>>(f2p, w3, f3pre, B * 256, 128, 64, part3);
    bn_finalize_kernel<<<dim3(128), 256, 0, stream>>>(part3, 64, 128, B * 256, g3, b3, sc3);
    pool_kernel<1><<<dim3(64, B), dim3(128, 2), 0, stream>>>(f3pre, idxE, f3p, 128, 256, 128, 128, 0, sc3);
    pool_kernel<0><<<dim3(32, B), dim3(128, 2), 0, stream>>>(f3p, idxF, hcat, 64, 128, 128, 512, 128, nullptr);

    // ---- stage 4
    gemm64_kernel<true><<<dim3(32, 4), 256, 0, stream>>>(f3p, w4, f4pre, B * 128, 256, 128, part4);
    bn_finalize_kernel<<<dim3(256), 256, 0, stream>>>(part4, 32, 256, B * 128, g4, b4, sc4);
    pool_kernel<1><<<dim3(64, B), dim3(256, 1), 0, stream>>>(f4pre, idxF, hcat, 64, 128, 256, 512, 256, sc4);

    // ---- stage 5
    gemm64_kernel<true><<<dim3(16, 16), 256, 0, stream>>>(hcat, w5, h5pre, B * 64, 1024, 512, part5);
    bn_finalize_kernel<<<dim3(1024), 256, 0, stream>>>(part5, 16, 1024, B * 64, g5, b5, sc5);
    global_pool_bn_kernel<<<dim3(4, B), 256, 0, stream>>>(h5pre, sc5, hg);

    // ---- head
    head_gemm_kernel<<<dim3(8, B), 64, 0, stream>>>(hg, l1w, nullptr, h6, 512, 2048);
    small_bn_kernel<<<dim3(8), 64, 0, stream>>>(h6, g6, b6, 512);
    head_gemm_kernel<<<dim3(4, B), 64, 0, stream>>>(h6, l2w, l2b, h7, 256, 512);
    small_bn_kernel<<<dim3(4), 64, 0, stream>>>(h7, g7, b7, 256);
    head_gemm_kernel<<<dim3(1, B), 64, 0, stream>>>(h7, l3w, l3b, outp, 40, 256);
}

// Round 6
// 361.599 us; speedup vs baseline: 29.0967x; 1.0361x over previous
//
#include <hip/hip_runtime.h>

#define BN_EPS 1e-5f
#define KNN 20

static inline int ceildiv(int a, int b) { return (a + b - 1) / b; }

// ---- 64-bit shuffles built from 32-bit primitives (segment width w) ----
__device__ __forceinline__ unsigned long long shfl64(unsigned long long v, int src, int w) {
    int lo = __shfl((int)(unsigned)(v & 0xffffffffull), src, w);
    int hi = __shfl((int)(unsigned)(v >> 32), src, w);
    return ((unsigned long long)(unsigned)hi << 32) | (unsigned)lo;
}
__device__ __forceinline__ unsigned long long shflup64(unsigned long long v, int d, int w) {
    int lo = __shfl_up((int)(unsigned)(v & 0xffffffffull), d, w);
    int hi = __shfl_up((int)(unsigned)(v >> 32), d, w);
    return ((unsigned long long)(unsigned)hi << 32) | (unsigned)lo;
}
__device__ __forceinline__ unsigned long long shflxor64(unsigned long long v, int m, int w) {
    int lo = __shfl_xor((int)(unsigned)(v & 0xffffffffull), m, w);
    int hi = __shfl_xor((int)(unsigned)(v >> 32), m, w);
    return ((unsigned long long)(unsigned)hi << 32) | (unsigned)lo;
}

// ============ stage-1 moments (Σp, Σppᵀ) + per-point squared norms ============
__global__ void moments3_kernel(const float* __restrict__ x, int N,
                                float* __restrict__ part /*[B][9]*/,
                                float* __restrict__ norms /*[B][N]*/) {
    int b = blockIdx.x;
    int t = threadIdx.x;   // 256
    const float* xb = x + (size_t)b * 3 * N;
    float m[9] = {0, 0, 0, 0, 0, 0, 0, 0, 0};
    for (int n = t; n < N; n += 256) {
        float px = xb[n], py = xb[N + n], pz = xb[2 * N + n];
        norms[(size_t)b * N + n] = px * px + py * py + pz * pz;
        m[0] += px; m[1] += py; m[2] += pz;
        m[3] += px * px; m[4] += py * py; m[5] += pz * pz;
        m[6] += px * py; m[7] += px * pz; m[8] += py * pz;
    }
#pragma unroll
    for (int o = 32; o; o >>= 1)
#pragma unroll
        for (int i = 0; i < 9; ++i) m[i] += __shfl_down(m[i], o);
    __shared__ float red[4][9];
    if ((t & 63) == 0)
#pragma unroll
        for (int i = 0; i < 9; ++i) red[t >> 6][i] = m[i];
    __syncthreads();
    if (t == 0) {
#pragma unroll
        for (int i = 0; i < 9; ++i)
            part[b * 9 + i] = red[0][i] + red[1][i] + red[2][i] + red[3][i];
    }
}

// ============ KNN: 2 queries per wave (32-lane segments), packed u64 keys ====
// key = (ordered(d2) << 32) | idx  -> u64 '<' is exactly jax top_k's
// (smallest d2, lowest index first) order. Lane sl (0..31) of each segment
// holds the sl-th best key; list init via 32-element bitonic sort of tile 0;
// later tiles insert ballot-gated survivors via a cross-lane shift, both
// segments' chains sharing the same wave instructions.
__global__ void knn_all_kernel(const float* __restrict__ x, const float* __restrict__ norms,
                               int Nstride,
                               int* __restrict__ iA, int* __restrict__ iB,
                               int* __restrict__ iC, int* __restrict__ iD,
                               int* __restrict__ iE, int* __restrict__ iF) {
    int b = blockIdx.y;
    int bx = blockIdx.x;
    int M, N; int* out; int qbase;
    if (bx < 128)      { M = 1024; N = 4096; out = iA; qbase = bx * 8; }
    else if (bx < 136) { M = 64;   N = 1024; out = iB; qbase = (bx - 128) * 8; }
    else if (bx < 168) { M = 256;  N = 1024; out = iC; qbase = (bx - 136) * 8; }
    else if (bx < 176) { M = 64;   N = 256;  out = iD; qbase = (bx - 168) * 8; }
    else if (bx < 192) { M = 128;  N = 256;  out = iE; qbase = (bx - 176) * 8; }
    else               { M = 64;   N = 128;  out = iF; qbase = (bx - 192) * 8; }
    int wave = threadIdx.x >> 6;
    int lane = threadIdx.x & 63;
    int sl = lane & 31;          // segment lane
    int half = lane >> 5;        // which query of the pair
    int q = qbase + wave * 2 + half;
    const float* xb = x + (size_t)b * 3 * Nstride;
    const float* nb = norms + (size_t)b * Nstride;
    float qx = xb[q], qy = xb[Nstride + q], qz = xb[2 * Nstride + q];
    float qq = nb[q];

    auto mkkey = [&](int j) -> unsigned long long {
        float cxv = xb[j], cyv = xb[Nstride + j], czv = xb[2 * Nstride + j];
        float d2 = qq + nb[j] - 2.f * (qx * cxv + qy * cyv + qz * czv);
        unsigned u = __float_as_uint(d2);
        unsigned ok = (u & 0x80000000u) ? ~u : (u | 0x80000000u);
        return ((unsigned long long)ok << 32) | (unsigned)j;
    };

    // ---- tile 0: bitonic ascending sort of 32 keys per segment
    unsigned long long lk = mkkey(sl);
#pragma unroll
    for (int size = 2; size <= 32; size <<= 1) {
#pragma unroll
        for (int stride = size >> 1; stride >= 1; stride >>= 1) {
            unsigned long long p = shflxor64(lk, stride, 32);
            bool ascend = (sl & size) == 0;
            bool low = (sl & stride) == 0;
            bool keepMin = (ascend == low);
            bool pLess = p < lk;
            lk = (keepMin == pLess) ? p : lk;
        }
    }
    unsigned long long wk = shfl64(lk, 19, 32);   // 20th-best per segment

    // ---- remaining tiles
    for (int j0 = 32; j0 < N; j0 += 32) {
        unsigned long long ck = mkkey(j0 + sl);
        unsigned long long msk = __ballot(ck < wk);
        if (msk) {
            unsigned mlo = (unsigned)msk, mhi = (unsigned)(msk >> 32);
            while (mlo | mhi) {
                int slo = __ffs((int)mlo) - 1;
                int shi = __ffs((int)mhi) - 1;
                int src = half ? shi : slo;
                unsigned long long kb = shfl64(ck, src & 31, 32);
                bool have = half ? (mhi != 0) : (mlo != 0);
                unsigned long long kk = have ? kb : ~0ull;
                unsigned long long up = shflup64(lk, 1, 32);
                bool c = kk < lk;
                bool cp = (sl != 0) && (kk < up);
                lk = c ? (cp ? up : kk) : lk;
                mlo &= mlo - 1;
                mhi &= mhi - 1;
            }
            wk = shfl64(lk, 19, 32);
        }
    }
    if (sl < KNN) out[((size_t)b * M + q) * KNN + sl] = (int)(unsigned)(lk & 0xffffffffull);
}

// ============ stage-1 pool: fused finalize1 + gather + dot + bn + lrelu ======
__global__ void pool1_kernel(const float* __restrict__ x, int N, const int* __restrict__ idxA,
                             const float* __restrict__ w1, const float* __restrict__ mom,
                             const float* __restrict__ g, const float* __restrict__ bb,
                             float Rinv, int Bn, float* __restrict__ out, int M) {
    __shared__ float S[9];
    __shared__ float sca[64], shb[64];
    int c = threadIdx.x;                    // 64
    int tid = threadIdx.y * 64 + c;
    if (tid < 9) {
        float s = 0.f;
        for (int bi = 0; bi < Bn; ++bi) s += mom[bi * 9 + tid];
        S[tid] = s;
    }
    __syncthreads();
    if (tid < 64) {
        float wx = w1[tid * 3], wy = w1[tid * 3 + 1], wz = w1[tid * 3 + 2];
        float mean = (wx * S[0] + wy * S[1] + wz * S[2]) * Rinv;
        float e2 = (wx * wx * S[3] + wy * wy * S[4] + wz * wz * S[5] +
                    2.f * (wx * wy * S[6] + wx * wz * S[7] + wy * wz * S[8])) * Rinv;
        float var = e2 - mean * mean;
        float a = g[tid] * rsqrtf(var + BN_EPS);
        sca[tid] = a;
        shb[tid] = bb[tid] - mean * a;
    }
    __syncthreads();
    int m = blockIdx.x * 4 + threadIdx.y;
    int b = blockIdx.y;
    const float* xb = x + (size_t)b * 3 * N;
    const int* ip = idxA + ((size_t)b * M + m) * KNN;
    float wx = w1[c * 3], wy = w1[c * 3 + 1], wz = w1[c * 3 + 2];
    float mx = -3.4e38f, mn = 3.4e38f;
#pragma unroll
    for (int k = 0; k < KNN; ++k) {
        int j = ip[k];
        float d = wx * xb[j] + wy * xb[N + j] + wz * xb[2 * N + j];
        mx = fmaxf(mx, d); mn = fminf(mn, d);
    }
    float a = sca[c];
    float v = a * (a >= 0.f ? mx : mn) + shb[c];
    out[((size_t)b * M + m) * 64 + c] = v >= 0.f ? v : 0.2f * v;
}

// ============ generic gather pool; MODE1 applies bn+lrelu via min/max =======
template <int MODE>
__global__ void pool_kernel(const float* __restrict__ f, const int* __restrict__ idx,
                            float* __restrict__ out, int M, int Nf, int C,
                            int out_stride, int out_off, const float* __restrict__ scsh) {
    int c = threadIdx.x;                               // blockDim.x == C
    int m = blockIdx.x * blockDim.y + threadIdx.y;
    int b = blockIdx.y;
    const int* ip = idx + ((size_t)b * M + m) * KNN;
    const float* fb = f + (size_t)b * Nf * C;
    float mx = -3.4e38f, mn = 3.4e38f;
#pragma unroll
    for (int k = 0; k < KNN; ++k) {
        int j = ip[k];
        float v = fb[(size_t)j * C + c];
        mx = fmaxf(mx, v);
        if (MODE) mn = fminf(mn, v);
    }
    float v;
    if (MODE) {
        float a = scsh[c];
        v = a * (a >= 0.f ? mx : mn) + scsh[C + c];
        v = v >= 0.f ? v : 0.2f * v;
    } else v = mx;
    out[((size_t)b * M + m) * out_stride + out_off + c] = v;
}

// ============ 64x64-tile GEMM, 4x4/thread, optional BN-stats epilogue =======
template <bool STATS>
__global__ void gemm64_kernel(const float* __restrict__ A, const float* __restrict__ W,
                              float* __restrict__ Cout, int M, int N, int K,
                              float* __restrict__ part /*[M/64][2][N]*/) {
    __shared__ float As[16][65], Ws[16][65];
    int t = threadIdx.x;
    int tx = t & 15, ty = t >> 4;
    int bm = blockIdx.x, bn = blockIdx.y;
    const float* Ab = A + (size_t)bm * 64 * K;
    const float* Wb = W + (size_t)bn * 64 * K;
    float acc[4][4] = {};
    for (int k0 = 0; k0 < K; k0 += 16) {
#pragma unroll
        for (int r = 0; r < 4; ++r) {
            int row = (t >> 4) + r * 16;
            As[t & 15][row] = Ab[(size_t)row * K + k0 + (t & 15)];
            Ws[t & 15][row] = Wb[(size_t)row * K + k0 + (t & 15)];
        }
        __syncthreads();
#pragma unroll
        for (int kk = 0; kk < 16; ++kk) {
            float a4[4], w4[4];
#pragma unroll
            for (int i = 0; i < 4; ++i) a4[i] = As[kk][ty * 4 + i];
#pragma unroll
            for (int j = 0; j < 4; ++j) w4[j] = Ws[kk][tx * 4 + j];
#pragma unroll
            for (int i = 0; i < 4; ++i)
#pragma unroll
                for (int j = 0; j < 4; ++j) acc[i][j] += a4[i] * w4[j];
        }
        __syncthreads();
    }
#pragma unroll
    for (int i = 0; i < 4; ++i) {
        float4 v = make_float4(acc[i][0], acc[i][1], acc[i][2], acc[i][3]);
        *(float4*)&Cout[(size_t)(bm * 64 + ty * 4 + i) * N + bn * 64 + tx * 4] = v;
    }
    if (STATS) {
        __shared__ float2 sred[16][64];
#pragma unroll
        for (int j = 0; j < 4; ++j) {
            float s = 0.f, q = 0.f;
#pragma unroll
            for (int i = 0; i < 4; ++i) { s += acc[i][j]; q += acc[i][j] * acc[i][j]; }
            sred[ty][tx * 4 + j] = make_float2(s, q);
        }
        __syncthreads();
        if (t < 64) {
            float s = 0.f, q = 0.f;
#pragma unroll
            for (int r = 0; r < 16; ++r) { s += sred[r][t].x; q += sred[r][t].y; }
            part[(size_t)bm * 2 * N + bn * 64 + t] = s;
            part[(size_t)bm * 2 * N + N + bn * 64 + t] = q;
        }
    }
}

// partials -> scale/shift
__global__ void bn_finalize_kernel(const float* __restrict__ part, int nparts, int C, int R,
                                   const float* __restrict__ g, const float* __restrict__ bb,
                                   float* __restrict__ scsh) {
    int c = blockIdx.x;
    int t = threadIdx.x;   // 256
    float s = 0.f, q = 0.f;
    for (int k = t; k < nparts; k += 256) {
        s += part[(size_t)k * 2 * C + c];
        q += part[(size_t)k * 2 * C + C + c];
    }
#pragma unroll
    for (int o = 32; o; o >>= 1) { s += __shfl_down(s, o); q += __shfl_down(q, o); }
    __shared__ float2 red[4];
    if ((t & 63) == 0) red[t >> 6] = make_float2(s, q);
    __syncthreads();
    if (t == 0) {
        s = red[0].x + red[1].x + red[2].x + red[3].x;
        q = red[0].y + red[1].y + red[2].y + red[3].y;
        float mean = s / (float)R;
        float var = q / (float)R - mean * mean;
        float a = g[c] * rsqrtf(var + BN_EPS);
        scsh[c] = a;
        scsh[C + c] = bb[c] - mean * a;
    }
}

// ============ global max+mean pool with fused bn+lrelu ============
__global__ void global_pool_bn_kernel(const float* __restrict__ h,
                                      const float* __restrict__ scsh,
                                      float* __restrict__ out) {
    int c = blockIdx.x * 256 + threadIdx.x;   // C=1024
    int b = blockIdx.y;
    const float* hb = h + (size_t)b * 64 * 1024;
    float a = scsh[c], sh = scsh[1024 + c];
    float mx = -3.4e38f, s = 0.f;
    for (int r = 0; r < 64; ++r) {
        float v = a * hb[r * 1024 + c] + sh;
        v = v >= 0.f ? v : 0.2f * v;
        mx = fmaxf(mx, v); s += v;
    }
    out[b * 2048 + c] = mx;
    out[b * 2048 + 1024 + c] = s * (1.f / 64.f);
}

// ============ head GEMM: one thread per output, float4 dot over K ============
__global__ void head_gemm_kernel(const float* __restrict__ A, const float* __restrict__ W,
                                 const float* __restrict__ bias, float* __restrict__ out,
                                 int N, int K) {
    int n = blockIdx.x * 64 + threadIdx.x;
    int m = blockIdx.y;
    if (n >= N) return;
    const float4* a4 = (const float4*)(A + (size_t)m * K);
    const float4* w4 = (const float4*)(W + (size_t)n * K);
    int K4 = K >> 2;
    float acc0 = 0.f, acc1 = 0.f, acc2 = 0.f, acc3 = 0.f;
    for (int k = 0; k < K4; ++k) {
        float4 a = a4[k], w = w4[k];
        acc0 = fmaf(a.x, w.x, acc0);
        acc1 = fmaf(a.y, w.y, acc1);
        acc2 = fmaf(a.z, w.z, acc2);
        acc3 = fmaf(a.w, w.w, acc3);
    }
    float r = (acc0 + acc1) + (acc2 + acc3);
    if (bias) r += bias[n];
    out[(size_t)m * N + n] = r;
}

// BN over R=16 rows, stats+apply in one kernel
__global__ void small_bn_kernel(float* __restrict__ y, const float* __restrict__ g,
                                const float* __restrict__ bb, int C) {
    int c = blockIdx.x * 64 + threadIdx.x;
    if (c >= C) return;
    float vals[16];
    float s = 0.f, q = 0.f;
#pragma unroll
    for (int r = 0; r < 16; ++r) {
        float v = y[r * C + c];
        vals[r] = v; s += v; q += v * v;
    }
    float mean = s * (1.f / 16.f);
    float var = q * (1.f / 16.f) - mean * mean;
    float a = g[c] * rsqrtf(var + BN_EPS);
    float sh = bb[c] - mean * a;
#pragma unroll
    for (int r = 0; r < 16; ++r) {
        float v = a * vals[r] + sh;
        y[r * C + c] = v >= 0.f ? v : 0.2f * v;
    }
}

extern "C" void kernel_launch(void* const* d_in, const int* in_sizes, int n_in,
                              void* d_out, int out_size, void* d_ws, size_t ws_size,
                              hipStream_t stream) {
    const int B = 16, N = 4096;
    const float* x   = (const float*)d_in[0];
    const float* w1  = (const float*)d_in[1];
    const float* g1  = (const float*)d_in[2];
    const float* b1  = (const float*)d_in[3];
    const float* w2  = (const float*)d_in[4];
    const float* g2  = (const float*)d_in[5];
    const float* b2  = (const float*)d_in[6];
    const float* w3  = (const float*)d_in[7];
    const float* g3  = (const float*)d_in[8];
    const float* b3  = (const float*)d_in[9];
    const float* w4  = (const float*)d_in[10];
    const float* g4  = (const float*)d_in[11];
    const float* b4  = (const float*)d_in[12];
    const float* w5  = (const float*)d_in[13];
    const float* g5  = (const float*)d_in[14];
    const float* b5  = (const float*)d_in[15];
    const float* l1w = (const float*)d_in[16];
    const float* g6  = (const float*)d_in[17];
    const float* b6  = (const float*)d_in[18];
    const float* l2w = (const float*)d_in[19];
    const float* l2b = (const float*)d_in[20];
    const float* g7  = (const float*)d_in[21];
    const float* b7  = (const float*)d_in[22];
    const float* l3w = (const float*)d_in[23];
    const float* l3b = (const float*)d_in[24];
    float* outp = (float*)d_out;

    char* ws = (char*)d_ws;
    size_t off = 0;
    auto alloc = [&](size_t bytes) -> void* {
        void* p = ws + off;
        off += (bytes + 255) & ~(size_t)255;
        return p;
    };
    float* f1p   = (float*)alloc((size_t)B * 1024 * 64 * 4);
    float* f2pre = (float*)alloc((size_t)B * 1024 * 64 * 4);
    float* f2p   = (float*)alloc((size_t)B * 256 * 64 * 4);
    float* f3pre = (float*)alloc((size_t)B * 256 * 128 * 4);
    float* f3p   = (float*)alloc((size_t)B * 128 * 128 * 4);
    float* f4pre = (float*)alloc((size_t)B * 128 * 256 * 4);
    float* hcat  = (float*)alloc((size_t)B * 64 * 512 * 4);
    float* h5pre = (float*)alloc((size_t)B * 64 * 1024 * 4);
    float* hg    = (float*)alloc((size_t)B * 2048 * 4);
    float* h6    = (float*)alloc((size_t)B * 512 * 4);
    float* h7    = (float*)alloc((size_t)B * 256 * 4);
    int* idxA = (int*)alloc((size_t)B * 1024 * KNN * 4);
    int* idxB = (int*)alloc((size_t)B * 64 * KNN * 4);
    int* idxC = (int*)alloc((size_t)B * 256 * KNN * 4);
    int* idxD = (int*)alloc((size_t)B * 64 * KNN * 4);
    int* idxE = (int*)alloc((size_t)B * 128 * KNN * 4);
    int* idxF = (int*)alloc((size_t)B * 64 * KNN * 4);
    float* mom   = (float*)alloc((size_t)B * 9 * 4);
    float* norms = (float*)alloc((size_t)B * N * 4);
    float* part2 = (float*)alloc((size_t)256 * 2 * 64 * 4);
    float* part3 = (float*)alloc((size_t)64 * 2 * 128 * 4);
    float* part4 = (float*)alloc((size_t)32 * 2 * 256 * 4);
    float* part5 = (float*)alloc((size_t)16 * 2 * 1024 * 4);
    float* sc2 = (float*)alloc(2 * 64 * 4);
    float* sc3 = (float*)alloc(2 * 128 * 4);
    float* sc4 = (float*)alloc(2 * 256 * 4);
    float* sc5 = (float*)alloc(2 * 1024 * 4);

    // ---- moments + norms, then KNN (all 6 tasks, 2 queries/wave)
    moments3_kernel<<<dim3(B), 256, 0, stream>>>(x, N, mom, norms);
    knn_all_kernel<<<dim3(200, B), 256, 0, stream>>>(x, norms, N, idxA, idxB, idxC, idxD, idxE, idxF);

    // ---- stage 1 pool (conv1 features on the fly; finalize fused in-block)
    pool1_kernel<<<dim3(256, B), dim3(64, 4), 0, stream>>>(x, N, idxA, w1, mom, g1, b1,
                                                           1.f / (B * N), B, f1p, 1024);
    pool_kernel<0><<<dim3(16, B), dim3(64, 4), 0, stream>>>(f1p, idxB, hcat, 64, 1024, 64, 512, 0, nullptr);

    // ---- stage 2
    gemm64_kernel<true><<<dim3(256, 1), 256, 0, stream>>>(f1p, w2, f2pre, B * 1024, 64, 64, part2);
    bn_finalize_kernel<<<dim3(64), 256, 0, stream>>>(part2, 256, 64, B * 1024, g2, b2, sc2);
    pool_kernel<1><<<dim3(64, B), dim3(64, 4), 0, stream>>>(f2pre, idxC, f2p, 256, 1024, 64, 64, 0, sc2);
    pool_kernel<0><<<dim3(16, B), dim3(64, 4), 0, stream>>>(f2p, idxD, hcat, 64, 256, 64, 512, 64, nullptr);

    // ---- stage 3
    gemm64_kernel<true><<<dim3(64, 2), 256, 0, stream>>>(f2p, w3, f3pre, B * 256, 128, 64, part3);
    bn_finalize_kernel<<<dim3(128), 256, 0, stream>>>(part3, 64, 128, B * 256, g3, b3, sc3);
    pool_kernel<1><<<dim3(64, B), dim3(128, 2), 0, stream>>>(f3pre, idxE, f3p, 128, 256, 128, 128, 0, sc3);
    pool_kernel<0><<<dim3(32, B), dim3(128, 2), 0, stream>>>(f3p, idxF, hcat, 64, 128, 128, 512, 128, nullptr);

    // ---- stage 4
    gemm64_kernel<true><<<dim3(32, 4), 256, 0, stream>>>(f3p, w4, f4pre, B * 128, 256, 128, part4);
    bn_finalize_kernel<<<dim3(256), 256, 0, stream>>>(part4, 32, 256, B * 128, g4, b4, sc4);
    pool_kernel<1><<<dim3(64, B), dim3(256, 1), 0, stream>>>(f4pre, idxF, hcat, 64, 128, 256, 512, 256, sc4);

    // ---- stage 5
    gemm64_kernel<true><<<dim3(16, 16), 256, 0, stream>>>(hcat, w5, h5pre, B * 64, 1024, 512, part5);
    bn_finalize_kernel<<<dim3(1024), 256, 0, stream>>>(part5, 16, 1024, B * 64, g5, b5, sc5);
    global_pool_bn_kernel<<<dim3(4, B), 256, 0, stream>>>(h5pre, sc5, hg);

    // ---- head
    head_gemm_kernel<<<dim3(8, B), 64, 0, stream>>>(hg, l1w, nullptr, h6, 512, 2048);
    small_bn_kernel<<<dim3(8), 64, 0, stream>>>(h6, g6, b6, 512);
    head_gemm_kernel<<<dim3(4, B), 64, 0, stream>>>(h6, l2w, l2b, h7, 256, 512);
    small_bn_kernel<<<dim3(4), 64, 0, stream>>>(h7, g7, b7, 256);
    head_gemm_kernel<<<dim3(1, B), 64, 0, stream>>>(h7, l3w, l3b, outp, 40, 256);
}